// Round 3
// baseline (1196.115 us; speedup 1.0000x reference)
//
#include <hip/hip_runtime.h>
#include <hip/hip_fp16.h>
#include <math.h>

typedef unsigned long long u64;
typedef __attribute__((ext_vector_type(2))) float fv2;

#define NN 8192
#define EE 81920
#define E2C 1310720
#define HSZ (1 << 18)
#define HMASK (HSZ - 1)
#define NBIN 320     // dst >> 8 : bins of 256 edge-nodes
#define BCAP 4800    // Poisson(4096), +11 sigma
#define SBITS 17     // src index bits in packed u32 payload
#define MBLK 1024    // kMEGA grid: 4 blocks/CU x 256 CU, co-resident

__device__ __forceinline__ float wsum(float v) {
#pragma unroll
  for (int m = 32; m > 0; m >>= 1) v += __shfl_xor(v, m, 64);
  return v;
}
__device__ __forceinline__ float lrelu(float x) { return x > 0.f ? x : 0.2f * x; }
__device__ __forceinline__ unsigned packh2(float a, float b) {
  __half2 h = __floats2half2_rn(a, b);
  return *reinterpret_cast<unsigned*>(&h);
}
__device__ __forceinline__ void atomic_pk_add_f16(unsigned* addr, unsigned data) {
  asm volatile("global_atomic_pk_add_f16 %0, %1, off" :: "v"(addr), "v"(data) : "memory");
}
__device__ __forceinline__ int hfind(const int* __restrict__ keys, int key) {
  unsigned i = ((unsigned)key * 2654435761u) >> 14 & HMASK;
  while (true) {
    int k = keys[i];
    if (k == key) return (int)i;
    if (k == -1) return -1;
    i = (i + 1) & HMASK;
  }
}
// bf16 helpers
__device__ __forceinline__ float2 bf2f(unsigned u) {
  return make_float2(__uint_as_float(u << 16), __uint_as_float(u & 0xffff0000u));
}
__device__ __forceinline__ unsigned f2bf(float a, float b) {
  unsigned ua = __float_as_uint(a);
  ua = (ua + 0x7fffu + ((ua >> 16) & 1u)) >> 16;
  unsigned ub = __float_as_uint(b);
  ub = ((ub + 0x7fffu + ((ub >> 16) & 1u)) >> 16) << 16;
  return (ua & 0xffffu) | ub;
}
__device__ __forceinline__ unsigned f2bf1(float a) {
  unsigned ua = __float_as_uint(a);
  return (ua + 0x7fffu + ((ua >> 16) & 1u)) >> 16;
}
__device__ __forceinline__ float bf1f(unsigned u) { return __uint_as_float(u << 16); }
// fp8 e4m3 pack/unpack (HW cvt, gfx950 OCP)
__device__ __forceinline__ unsigned short f2fp8x2(float a, float b) {
  return (unsigned short)(__builtin_amdgcn_cvt_pk_fp8_f32(a, b, 0, false) & 0xffff);
}
__device__ __forceinline__ float2 fp8x2f(unsigned short v) {
  fv2 f = __builtin_amdgcn_cvt_pk_f32_fp8((int)(unsigned)v, false);
  return make_float2(f[0], f[1]);
}
// wave-uniform broadcast of lane k's value via scalar readlane (no LDS traffic)
__device__ __forceinline__ float rdlane(float v, int k) {
  return __uint_as_float(__builtin_amdgcn_readlane(__float_as_uint(v), k));
}

// device-scope grid barrier (generation-based, timeout-guarded: worst case is a
// wrong answer, never a hang). All MBLK blocks co-resident by capacity math.
__device__ __forceinline__ void gbar(unsigned* ctr, unsigned* gen) {
  __syncthreads();
  if (threadIdx.x == 0) {
    __threadfence();  // make prior global writes visible device-wide
    unsigned g = __hip_atomic_load(gen, __ATOMIC_RELAXED, __HIP_MEMORY_SCOPE_AGENT);
    unsigned a = __hip_atomic_fetch_add(ctr, 1u, __ATOMIC_ACQ_REL, __HIP_MEMORY_SCOPE_AGENT);
    if (a == MBLK - 1) {
      __hip_atomic_store(ctr, 0u, __ATOMIC_RELAXED, __HIP_MEMORY_SCOPE_AGENT);
      __hip_atomic_fetch_add(gen, 1u, __ATOMIC_ACQ_REL, __HIP_MEMORY_SCOPE_AGENT);
    } else {
      u64 t0 = __builtin_amdgcn_s_memrealtime();
      while (__hip_atomic_load(gen, __ATOMIC_ACQUIRE, __HIP_MEMORY_SCOPE_AGENT) == g) {
        __builtin_amdgcn_s_sleep(16);
        if (__builtin_amdgcn_s_memrealtime() - t0 > 50000000ull) break;  // anti-hang
      }
    }
  }
  __syncthreads();
}

// A: init + x->fp8 + per-block combo in LDS + node scalars + gb scalar. 512 blocks.
__global__ __launch_bounds__(256) void kA(const float* __restrict__ x,
                                          const float* __restrict__ embed,
                                          const float* __restrict__ gw,
                                          const float* __restrict__ att_s,
                                          const float* __restrict__ att_d,
                                          const float* __restrict__ lin_W,
                                          const float* __restrict__ gat_b,
                                          const float* __restrict__ lin_b,
                                          float4* __restrict__ pN, float4* __restrict__ qN,
                                          unsigned short* __restrict__ xbu,
                                          int* __restrict__ hKeys, unsigned* __restrict__ hPair,
                                          int* __restrict__ colCnt, float* __restrict__ gvec,
                                          unsigned* __restrict__ done, unsigned* __restrict__ gCur,
                                          float* __restrict__ gbS, unsigned* __restrict__ bar) {
  __shared__ float sm[768];  // cA | cD | cZ
  int t = threadIdx.x, bid = blockIdx.x;
  int lane = t & 63, wv = t >> 6;
  for (int i = bid * 256 + t; i < HSZ; i += 512 * 256) { hKeys[i] = -1; hPair[i] = 0u; }
  for (int i = bid * 256 + t; i < NN; i += 512 * 256) colCnt[i] = 0;
  if (bid == 0) {
    for (int i = t; i < 2048; i += 256) gvec[i] = 0.f;  // 16 contention-spread copies
    if (t == 0) { *done = 0u; bar[0] = 0u; bar[1] = 0u; }
    for (int i = t; i < NBIN; i += 256) gCur[i] = 0u;
    if (wv == 0) {  // gb = gat_b . lin_W + lin_b, hoisted out of the gate stage
      float gb = wsum(gat_b[lane] * lin_W[lane]);
      if (lane == 0) *gbS = gb + lin_b[0];
    }
  }
  {  // x -> fp8 e4m3: thread handles node bid*16+(t>>4), dims (t&15)*8 .. +7
    int n = bid * 16 + (t >> 4);
    int dp = (t & 15) * 8;
    const float4* x4 = (const float4*)(x + n * 128 + dp);
    float4 a = x4[0], b = x4[1];
    unsigned p0 = f2fp8x2(a.x, a.y), p1 = f2fp8x2(a.z, a.w);
    unsigned p2 = f2fp8x2(b.x, b.y), p3 = f2fp8x2(b.z, b.w);
    ((uint2*)xbu)[n * 16 + (t & 15)] = make_uint2(p0 | (p1 << 16), p2 | (p3 << 16));
  }
  {
    float sa = 0.f, sd = 0.f, sz = 0.f;
#pragma unroll 8
    for (int k = 0; k < 64; k++) {
      float w = gw[t * 64 + k];
      sa += w * att_s[k]; sd += w * att_d[k]; sz += w * lin_W[k];
    }
    sm[t] = sa; sm[256 + t] = sd; sm[512 + t] = sz;
  }
  __syncthreads();
#pragma unroll
  for (int j = 0; j < 4; j++) {
    int n = bid * 16 + wv * 4 + j;
    float e0 = embed[n * 128 + lane], e1 = embed[n * 128 + 64 + lane];
    float pA = wsum(e0 * sm[lane] + e1 * sm[64 + lane]);
    float qA = wsum(e0 * sm[128 + lane] + e1 * sm[192 + lane]);
    float pD = wsum(e0 * sm[256 + lane] + e1 * sm[320 + lane]);
    float qD = wsum(e0 * sm[384 + lane] + e1 * sm[448 + lane]);
    float pZ = wsum(e0 * sm[512 + lane] + e1 * sm[576 + lane]);
    float qZ = wsum(e0 * sm[640 + lane] + e1 * sm[704 + lane]);
    if (lane == 0) pN[n] = make_float4(pA, pD, pZ, 0.f);
    if (lane == 1) qN[n] = make_float4(qA, qD, qZ, 0.f);
  }
}

// gather one node's aggregated features (fp8 rows = 128B, 4-wide ILP); returns f32 pair
__device__ __forceinline__ float2 gatherNode(const unsigned short* __restrict__ xb, int n, int lane,
                                             const int* __restrict__ colOffs,
                                             const unsigned* __restrict__ csrW) {
  float2 sf = fp8x2f(xb[n * 64 + lane]);
  float a0 = sf.x, a1 = sf.y, ws = 0.f;
  int off = colOffs[n], end = colOffs[n + 1];
  int i = off;
  for (; i + 4 <= end; i += 4) {
    unsigned q0 = csrW[i], q1 = csrW[i + 1], q2 = csrW[i + 2], q3 = csrW[i + 3];
    unsigned short u0 = xb[(q0 & 0x1fff) * 64 + lane];
    unsigned short u1 = xb[(q1 & 0x1fff) * 64 + lane];
    unsigned short u2 = xb[(q2 & 0x1fff) * 64 + lane];
    unsigned short u3 = xb[(q3 & 0x1fff) * 64 + lane];
    float w0 = bf1f(q0 >> 16), w1 = bf1f(q1 >> 16);
    float w2 = bf1f(q2 >> 16), w3 = bf1f(q3 >> 16);
    ws += w0 + w1 + w2 + w3;
    float2 f0 = fp8x2f(u0), f1 = fp8x2f(u1), f2v = fp8x2f(u2), f3 = fp8x2f(u3);
    a0 += w0 * f0.x + w1 * f1.x + w2 * f2v.x + w3 * f3.x;
    a1 += w0 * f0.y + w1 * f1.y + w2 * f2v.y + w3 * f3.y;
  }
  for (; i < end; i++) {
    unsigned q = csrW[i];
    unsigned short u = xb[(q & 0x1fff) * 64 + lane];
    float w = bf1f(q >> 16);
    ws += w;
    float2 f = fp8x2f(u);
    a0 += w * f.x;
    a1 += w * f.y;
  }
  float inv = 1.f / (1.f + ws);
  return make_float2(a0 * inv, a1 * inv);
}

// ---- GEMM: T in registers (lane L holds dims 2L,2L+1), W bf16 in 32KB LDS,
//      T[k] broadcast via scalar readlane ----
#define GEMM2(tv, acc)                                                   \
  {                                                                      \
    _Pragma("unroll") for (int j = 0; j < 2; j++) acc[j] = make_float2(0.f, 0.f); \
    _Pragma("unroll 16") for (int k2 = 0; k2 < 64; k2++) {               \
      float2 w0 = bf2f(Wl[(2 * k2) * 64 + lane]);                        \
      float2 w1 = bf2f(Wl[(2 * k2 + 1) * 64 + lane]);                    \
      _Pragma("unroll") for (int j = 0; j < 2; j++) {                    \
        float bx = rdlane(tv[j].x, k2);                                  \
        float by = rdlane(tv[j].y, k2);                                  \
        acc[j].x += bx * w0.x + by * w1.x;                               \
        acc[j].y += bx * w0.y + by * w1.y;                               \
      }                                                                  \
    }                                                                    \
  }

// GCN layer stage inside kMEGA: stage W into LDS, gather 2 nodes/wave, GEMM, fp8 out.
__device__ __forceinline__ void gcnStage(const unsigned short* __restrict__ xb,
                                         const float* __restrict__ W,
                                         unsigned* Wl,
                                         const int* __restrict__ colOffs,
                                         const unsigned* __restrict__ csrW,
                                         int bid, int t, int lane, int wv,
                                         unsigned short* __restrict__ outB) {
  const float4* W4 = (const float4*)W;
  for (int i = t; i < 4096; i += 256) {
    float4 a = W4[i];
    ((uint2*)Wl)[i] = make_uint2(f2bf(a.x, a.y), f2bf(a.z, a.w));
  }
  int nb = bid * 8;
  float2 tv[2];
#pragma unroll
  for (int j = 0; j < 2; j++)
    tv[j] = gatherNode(xb, nb + wv * 2 + j, lane, colOffs, csrW);
  __syncthreads();
  float2 acc[2];
  GEMM2(tv, acc)
#pragma unroll
  for (int j = 0; j < 2; j++) {
    int n = nb + wv * 2 + j;
    outB[n * 64 + lane] = f2fp8x2(fmaxf(acc[j].x, 0.f), fmaxf(acc[j].y, 0.f));
  }
}

// MEGA: [kB+kC | kD | kE | kF(W1) | kF(W2) | kH(W3)] with grid barriers.
// 1024 blocks x 256 thr, 32KB LDS, <=128 VGPR => exactly 4 blocks/CU co-resident.
__global__ __launch_bounds__(256, 4) void kMEGA(
    const int* __restrict__ row, const int* __restrict__ col,
    const float4* __restrict__ pN, const float4* __restrict__ qN,
    float2* __restrict__ asz, float* __restrict__ ad,
    int* __restrict__ colCnt,
    const int* __restrict__ src2, const int* __restrict__ dst2,
    unsigned* __restrict__ gCur, unsigned* __restrict__ bucket,
    const float* __restrict__ gbS, const float* __restrict__ noise,
    const float* __restrict__ tmp,
    int* __restrict__ hKeys, unsigned* __restrict__ hPair,
    int* __restrict__ eslot, int* __restrict__ colOffs, int* __restrict__ colCur,
    unsigned* __restrict__ csrW,
    const unsigned short* __restrict__ xbu,
    unsigned short* __restrict__ H1u, unsigned short* __restrict__ H2u,
    const float* __restrict__ W1, const float* __restrict__ W2,
    const float* __restrict__ W3, const float* __restrict__ Wc,
    float* __restrict__ gvec, unsigned* __restrict__ done,
    float* __restrict__ out, unsigned* __restrict__ bar) {
  __shared__ unsigned Wl[8192];  // 32KB union: hist/base/lcur | acc/adl/sd32 | W bf16
  int bid = blockIdx.x, t = threadIdx.x;
  int lane = t & 63, wv = t >> 6;
  unsigned* bctr = bar;
  unsigned* bgen = bar + 1;

  // ---- S0: per-edge scalars + edge2 binning (blocks 0..319) ----
  if (bid < NBIN) {
    unsigned* hist = Wl;
    unsigned* base = Wl + NBIN;
    unsigned* lcur = Wl + 2 * NBIN;
    for (int i = t; i < NBIN; i += 256) { hist[i] = 0u; lcur[i] = 0u; }
    int blockBase = bid * 4096;
    {
      int e = bid * 256 + t;
      int r = row[e], c = col[e];
      float4 p = pN[r];
      float4 q = qN[c];
      asz[e] = make_float2(p.x + q.x, p.z + q.z);  // {a_s, z}
      ad[e] = p.y + q.y;
      atomicAdd(&colCnt[c], 1);
    }
    __syncthreads();
    int4 dv[4];
#pragma unroll
    for (int j = 0; j < 4; j++) {
      dv[j] = *(const int4*)&dst2[blockBase + j * 1024 + t * 4];
      atomicAdd(&hist[dv[j].x >> 8], 1u);
      atomicAdd(&hist[dv[j].y >> 8], 1u);
      atomicAdd(&hist[dv[j].z >> 8], 1u);
      atomicAdd(&hist[dv[j].w >> 8], 1u);
    }
    __syncthreads();
    for (int i = t; i < NBIN; i += 256)
      if (hist[i]) base[i] = atomicAdd(&gCur[i], hist[i]);
    __syncthreads();
#pragma unroll
    for (int j = 0; j < 4; j++) {
      int4 sv = *(const int4*)&src2[blockBase + j * 1024 + t * 4];
      int ss[4] = {sv.x, sv.y, sv.z, sv.w};
      int dd[4] = {dv[j].x, dv[j].y, dv[j].z, dv[j].w};
#pragma unroll
      for (int k = 0; k < 4; k++) {
        int s = ss[k], d = dd[k];
        int b = d >> 8;
        unsigned r = atomicAdd(&lcur[b], 1u);
        unsigned pos = base[b] + r;
        if (pos < BCAP) bucket[(size_t)b * BCAP + pos] = ((unsigned)(d & 255) << SBITS) | (unsigned)s;
      }
    }
  }
  gbar(bctr, bgen);

  // ---- S1: per-bin reduce + gate + hash insert (0..319); colCnt scan (320) ----
  if (bid <= NBIN) {
    if (bid == NBIN) {  // scan block
      int* sd32 = (int*)(Wl + 768);
      int beg = t * 32;
      int s = 0;
#pragma unroll 8
      for (int i = 0; i < 32; i++) s += colCnt[beg + i];
      sd32[t] = s;
      __syncthreads();
      for (int o = 1; o < 256; o <<= 1) {
        int v = (t >= o) ? sd32[t - o] : 0;
        __syncthreads();
        sd32[t] += v;
        __syncthreads();
      }
      int run = (t == 0) ? 0 : sd32[t - 1];
      for (int i = 0; i < 32; i++) {
        colOffs[beg + i] = run;
        colCur[beg + i] = run;
        run += colCnt[beg + i];
      }
      if (t == 255) colOffs[NN] = run;
    } else {
      float* acc = (float*)Wl;          // 512 f32
      float* adl = (float*)Wl + 512;    // 256 f32
      acc[2 * t] = 0.f; acc[2 * t + 1] = 0.f; adl[t] = ad[bid * 256 + t];
      __syncthreads();
      int cnt = min((int)gCur[bid], BCAP);
      const unsigned* bp = bucket + (size_t)bid * BCAP;
      const unsigned SM = (1u << SBITS) - 1;
      int i = t;
      for (; i + 768 < cnt; i += 1024) {
        unsigned u0 = bp[i], u1 = bp[i + 256], u2 = bp[i + 512], u3 = bp[i + 768];
        float2 az0 = asz[u0 & SM], az1 = asz[u1 & SM], az2 = asz[u2 & SM], az3 = asz[u3 & SM];
        int l0 = u0 >> SBITS, l1 = u1 >> SBITS, l2 = u2 >> SBITS, l3 = u3 >> SBITS;
        float ea0 = __expf(lrelu(az0.x + adl[l0]));
        float ea1 = __expf(lrelu(az1.x + adl[l1]));
        float ea2 = __expf(lrelu(az2.x + adl[l2]));
        float ea3 = __expf(lrelu(az3.x + adl[l3]));
        atomicAdd(&acc[2 * l0], ea0); atomicAdd(&acc[2 * l0 + 1], ea0 * az0.y);
        atomicAdd(&acc[2 * l1], ea1); atomicAdd(&acc[2 * l1 + 1], ea1 * az1.y);
        atomicAdd(&acc[2 * l2], ea2); atomicAdd(&acc[2 * l2 + 1], ea2 * az2.y);
        atomicAdd(&acc[2 * l3], ea3); atomicAdd(&acc[2 * l3 + 1], ea3 * az3.y);
      }
      for (; i < cnt; i += 256) {
        unsigned u = bp[i];
        float2 az = asz[u & SM];
        int l = u >> SBITS;
        float ea = __expf(lrelu(az.x + adl[l]));
        atomicAdd(&acc[2 * l], ea);
        atomicAdd(&acc[2 * l + 1], ea * az.y);
      }
      __syncthreads();
      float gb = *gbS;
      float itmp = 1.f / tmp[0];
      {
        int e = bid * 256 + t;
        float2 szv = asz[e];
        float eself = __expf(lrelu(szv.x + adl[t]));  // softmax shift-invariant
        float la = (acc[2 * t + 1] + eself * szv.y) / (acc[2 * t] + eself) + gb;
        float ns = noise[e];
        float g = (logf(ns) - log1pf(-ns) + la) * itmp;
        float gate = 1.f / (1.f + __expf(-g));
        int key = row[e] * NN + col[e];
        unsigned hi = ((unsigned)key * 2654435761u) >> 14 & HMASK;
        while (true) {
          int old = atomicCAS(&hKeys[hi], -1, key);
          if (old == -1 || old == key) break;
          hi = (hi + 1) & HMASK;
        }
        eslot[e] = (int)hi;  // forward slot for the kE stage (skips its probe)
        atomic_pk_add_f16(&hPair[hi], packh2(1.0f, gate));
      }
    }
  }
  gbar(bctr, bgen);

  // ---- S2: edge_mask -> w, CSR scatter (blocks 0..319) ----
  if (bid < NBIN) {
    int e = bid * 256 + t;
    int r = row[e], c = col[e];
    int s1 = eslot[e];
    unsigned u1 = hPair[s1];
    __half2 h1 = *reinterpret_cast<__half2*>(&u1);
    float cv = __low2float(h1), g1 = __high2float(h1);
    int s2 = hfind(hKeys, c * NN + r);
    float g2 = 0.f;
    if (s2 >= 0) {
      unsigned u2 = hPair[s2];
      g2 = __high2float(*reinterpret_cast<__half2*>(&u2));
    }
    float em = cv * 0.5f * (g1 + g2);
    float w = 1.f / (1.f + __expf(-em));
    int pos = atomicAdd(&colCur[c], 1);
    csrW[pos] = (f2bf1(w) << 16) | (unsigned)r;
  }
  gbar(bctr, bgen);

  // ---- S3: GCN layer 1 ----
  gcnStage(xbu, W1, Wl, colOffs, csrW, bid, t, lane, wv, H1u);
  gbar(bctr, bgen);

  // ---- S4: GCN layer 2 ----
  gcnStage(H1u, W2, Wl, colOffs, csrW, bid, t, lane, wv, H2u);
  gbar(bctr, bgen);

  // ---- S5: layer 3 + pool + classifier (kH body) ----
  {
    const float4* W4 = (const float4*)W3;
    for (int i = t; i < 4096; i += 256) {
      float4 a = W4[i];
      ((uint2*)Wl)[i] = make_uint2(f2bf(a.x, a.y), f2bf(a.z, a.w));
    }
    int nb = bid * 8;
    float2 tv[2];
#pragma unroll
    for (int j = 0; j < 2; j++)
      tv[j] = gatherNode(H2u, nb + wv * 2 + j, lane, colOffs, csrW);
    __syncthreads();
    float2 acc[2];
    GEMM2(tv, acc)
    // pool: H3 never written to memory
    float s0 = fmaxf(acc[0].x, 0.f) + fmaxf(acc[1].x, 0.f);
    float s1 = fmaxf(acc[0].y, 0.f) + fmaxf(acc[1].y, 0.f);
    __syncthreads();  // GEMM done reading Wl; reuse as scratch
    float* gpart = (float*)Wl;
    unsigned* flagp = (unsigned*)Wl + 600;
    if (t < 128) gpart[t] = 0.f;
    __syncthreads();
    atomicAdd(&gpart[2 * lane], s0);
    atomicAdd(&gpart[2 * lane + 1], s1);
    __syncthreads();
    if (t < 128) atomicAdd(&gvec[((bid & 15) << 7) + t], gpart[t]);
    asm volatile("s_waitcnt vmcnt(0)" ::: "memory");  // gvec atomics complete (memory-side)
    __syncthreads();
    if (t == 0) *flagp = (atomicAdd(done, 1u) == (unsigned)(gridDim.x - 1)) ? 1u : 0u;
    __syncthreads();
    if (*flagp) {
      float* f0 = (float*)Wl + 256;
      float* f1 = (float*)Wl + 384;
      if (t < 128) {
        float gj = 0.f;
#pragma unroll
        for (int k = 0; k < 16; k++) gj += atomicAdd(&gvec[k * 128 + t], 0.f);  // memory-side reads
        gj *= (1.0f / 8192.0f);
        f0[t] = gj * Wc[t * 2 + 0];
        f1[t] = gj * Wc[t * 2 + 1];
      }
      __syncthreads();
      for (int o = 64; o > 0; o >>= 1) {
        if (t < o) { f0[t] += f0[t + o]; f1[t] += f1[t + o]; }
        __syncthreads();
      }
      if (t == 0) {
        float l0 = f0[0], l1 = f1[0];
        float m = fmaxf(l0, l1);
        float e0 = __expf(l0 - m), e1 = __expf(l1 - m);
        float inv = 1.f / (e0 + e1);
        out[0] = e0 * inv;
        out[1] = e1 * inv;
      }
    }
  }
}

extern "C" void kernel_launch(void* const* d_in, const int* in_sizes, int n_in,
                              void* d_out, int out_size, void* d_ws, size_t ws_size,
                              hipStream_t stream) {
  const float* x     = (const float*)d_in[0];
  const float* embed = (const float*)d_in[1];
  const float* noise = (const float*)d_in[2];
  const float* tmp   = (const float*)d_in[3];
  const float* gat_W = (const float*)d_in[4];
  const float* att_s = (const float*)d_in[5];
  const float* att_d = (const float*)d_in[6];
  const float* gat_b = (const float*)d_in[7];
  const float* lin_W = (const float*)d_in[8];
  const float* lin_b = (const float*)d_in[9];
  const float* W1    = (const float*)d_in[10];
  const float* W2    = (const float*)d_in[11];
  const float* W3    = (const float*)d_in[12];
  const float* Wc    = (const float*)d_in[13];
  const int* ei      = (const int*)d_in[14];
  const int* nei     = (const int*)d_in[15];
  const int* row = ei;
  const int* col = ei + EE;
  const int* src2 = nei;
  const int* dst2 = nei + E2C;
  float* out = (float*)d_out;

  // workspace layout (4-byte units); 16B/8B-aligned buffers first
  char* w8 = (char*)d_ws;
  size_t off = 0;
  auto alloc = [&](size_t units) -> void* {
    void* p = w8 + off * 4;
    off += units;
    return p;
  };
  float4*   pN      = (float4*)alloc(4 * NN);
  float4*   qN      = (float4*)alloc(4 * NN);
  float2*   asz     = (float2*)alloc(2 * EE);
  unsigned short* xbu = (unsigned short*)alloc(NN * 32);  // fp8x2 per lane
  unsigned short* H1u = (unsigned short*)alloc(NN * 32);
  unsigned short* H2u = (unsigned short*)alloc(NN * 32);
  unsigned* csrW    = (unsigned*)alloc(EE);
  float*    ad      = (float*)alloc(EE);
  int*      eslot   = (int*)alloc(EE);
  int*      colCnt  = (int*)alloc(NN);
  int*      colOffs = (int*)alloc(NN + 2);
  int*      colCur  = (int*)alloc(NN);
  int*      hKeys   = (int*)alloc(HSZ);
  unsigned* hPair   = (unsigned*)alloc(HSZ);
  unsigned* bucket  = (unsigned*)alloc((size_t)NBIN * BCAP);
  unsigned* gCur    = (unsigned*)alloc(NBIN);
  float*    gvec    = (float*)alloc(2048);  // 16 copies x 128
  unsigned* done    = (unsigned*)alloc(2);
  float*    gbS     = (float*)alloc(2);
  unsigned* bar     = (unsigned*)alloc(4);  // grid-barrier {ctr, gen}

  kA<<<512, 256, 0, stream>>>(x, embed, gat_W, att_s, att_d, lin_W, gat_b, lin_b,
                              pN, qN, xbu, hKeys, hPair, colCnt, gvec, done, gCur, gbS, bar);
  kMEGA<<<MBLK, 256, 0, stream>>>(row, col, pN, qN, asz, ad, colCnt, src2, dst2,
                                  gCur, bucket, gbS, noise, tmp, hKeys, hPair,
                                  eslot, colOffs, colCur, csrW, xbu, H1u, H2u,
                                  W1, W2, W3, Wc, gvec, done, out, bar);
}

// Round 5
// 1141.164 us; speedup vs baseline: 1.0482x; 1.0482x over previous
//
#include <hip/hip_runtime.h>
#include <hip/hip_fp16.h>
#include <math.h>

typedef unsigned long long u64;
typedef __attribute__((ext_vector_type(2))) float fv2;

#define NN 8192
#define EE 81920
#define E2C 1310720
#define HSZ (1 << 18)
#define HMASK (HSZ - 1)
#define NBIN 320     // dst >> 8 : bins of 256 edge-nodes
#define BCAP 4800    // Poisson(4096), +11 sigma
#define SBITS 17     // src index bits in packed u32 payload
#define MBLK 1024    // kMEGA grid: 4 blocks/CU x 256 CU, co-resident
#define GENOFF 1056  // gen word: 128B past arr[1024], own cache line

__device__ __forceinline__ float wsum(float v) {
#pragma unroll
  for (int m = 32; m > 0; m >>= 1) v += __shfl_xor(v, m, 64);
  return v;
}
__device__ __forceinline__ float lrelu(float x) { return x > 0.f ? x : 0.2f * x; }
__device__ __forceinline__ unsigned packh2(float a, float b) {
  __half2 h = __floats2half2_rn(a, b);
  return *reinterpret_cast<unsigned*>(&h);
}
__device__ __forceinline__ void atomic_pk_add_f16(unsigned* addr, unsigned data) {
  asm volatile("global_atomic_pk_add_f16 %0, %1, off" :: "v"(addr), "v"(data) : "memory");
}
__device__ __forceinline__ int hfind(const int* __restrict__ keys, int key) {
  unsigned i = ((unsigned)key * 2654435761u) >> 14 & HMASK;
  while (true) {
    int k = keys[i];
    if (k == key) return (int)i;
    if (k == -1) return -1;
    i = (i + 1) & HMASK;
  }
}
// bf16 helpers
__device__ __forceinline__ float2 bf2f(unsigned u) {
  return make_float2(__uint_as_float(u << 16), __uint_as_float(u & 0xffff0000u));
}
__device__ __forceinline__ unsigned f2bf(float a, float b) {
  unsigned ua = __float_as_uint(a);
  ua = (ua + 0x7fffu + ((ua >> 16) & 1u)) >> 16;
  unsigned ub = __float_as_uint(b);
  ub = ((ub + 0x7fffu + ((ub >> 16) & 1u)) >> 16) << 16;
  return (ua & 0xffffu) | ub;
}
__device__ __forceinline__ unsigned f2bf1(float a) {
  unsigned ua = __float_as_uint(a);
  return (ua + 0x7fffu + ((ua >> 16) & 1u)) >> 16;
}
__device__ __forceinline__ float bf1f(unsigned u) { return __uint_as_float(u << 16); }
// fp8 e4m3 pack/unpack (HW cvt, gfx950 OCP)
__device__ __forceinline__ unsigned short f2fp8x2(float a, float b) {
  return (unsigned short)(__builtin_amdgcn_cvt_pk_fp8_f32(a, b, 0, false) & 0xffff);
}
__device__ __forceinline__ float2 fp8x2f(unsigned short v) {
  fv2 f = __builtin_amdgcn_cvt_pk_f32_fp8((int)(unsigned)v, false);
  return make_float2(f[0], f[1]);
}
// wave-uniform broadcast of lane k's value via scalar readlane (no LDS traffic)
__device__ __forceinline__ float rdlane(float v, int k) {
  return __uint_as_float(__builtin_amdgcn_readlane(__float_as_uint(v), k));
}

// grid barrier v2: per-block arrive flags (plain release stores, 64 distinct
// lines) + block-0 leader sweep + gen word on its own line. No RMW anywhere.
// Timeout-guarded: worst case is a failed verify, never a hang.
__device__ __forceinline__ void gbar2(unsigned* __restrict__ arr, unsigned bno,
                                      int bid, int t) {
  unsigned* genp = arr + GENOFF;
  __syncthreads();
  if (t == 0) {
    __threadfence();  // drain this block's global writes (wb L2) before arrive
    __hip_atomic_store(&arr[bid], bno, __ATOMIC_RELEASE, __HIP_MEMORY_SCOPE_AGENT);
  }
  if (bid == 0) {
    u64 t0 = __builtin_amdgcn_s_memrealtime();
    for (;;) {
      unsigned a0 = __hip_atomic_load(&arr[t], __ATOMIC_ACQUIRE, __HIP_MEMORY_SCOPE_AGENT);
      unsigned a1 = __hip_atomic_load(&arr[t + 256], __ATOMIC_ACQUIRE, __HIP_MEMORY_SCOPE_AGENT);
      unsigned a2 = __hip_atomic_load(&arr[t + 512], __ATOMIC_ACQUIRE, __HIP_MEMORY_SCOPE_AGENT);
      unsigned a3 = __hip_atomic_load(&arr[t + 768], __ATOMIC_ACQUIRE, __HIP_MEMORY_SCOPE_AGENT);
      if (a0 >= bno && a1 >= bno && a2 >= bno && a3 >= bno) break;
      if (__builtin_amdgcn_s_memrealtime() - t0 > 5000000ull) break;  // anti-hang
      __builtin_amdgcn_s_sleep(4);
    }
    __syncthreads();  // all 256 leader threads observed their flags
    if (t == 0) __hip_atomic_store(genp, bno, __ATOMIC_RELEASE, __HIP_MEMORY_SCOPE_AGENT);
  } else {
    if (t == 0) {
      u64 t0 = __builtin_amdgcn_s_memrealtime();
      while (__hip_atomic_load(genp, __ATOMIC_ACQUIRE, __HIP_MEMORY_SCOPE_AGENT) < bno) {
        if (__builtin_amdgcn_s_memrealtime() - t0 > 5000000ull) break;  // anti-hang
        __builtin_amdgcn_s_sleep(16);
      }
    }
    __syncthreads();
  }
}

// A: init + x->fp8 + per-block combo in LDS + node scalars + gb scalar. 512 blocks.
__global__ __launch_bounds__(256) void kA(const float* __restrict__ x,
                                          const float* __restrict__ embed,
                                          const float* __restrict__ gw,
                                          const float* __restrict__ att_s,
                                          const float* __restrict__ att_d,
                                          const float* __restrict__ lin_W,
                                          const float* __restrict__ gat_b,
                                          const float* __restrict__ lin_b,
                                          float4* __restrict__ pN, float4* __restrict__ qN,
                                          unsigned short* __restrict__ xbu,
                                          int* __restrict__ hKeys, unsigned* __restrict__ hPair,
                                          int* __restrict__ colCnt, float* __restrict__ gvec,
                                          unsigned* __restrict__ done, unsigned* __restrict__ gCur,
                                          float* __restrict__ gbS, unsigned* __restrict__ barA) {
  __shared__ float sm[768];  // cA | cD | cZ
  int t = threadIdx.x, bid = blockIdx.x;
  int lane = t & 63, wv = t >> 6;
  for (int i = bid * 256 + t; i < HSZ; i += 512 * 256) { hKeys[i] = -1; hPair[i] = 0u; }
  for (int i = bid * 256 + t; i < NN; i += 512 * 256) colCnt[i] = 0;
  { int i = bid * 256 + t; if (i < 1088) barA[i] = 0u; }  // arrive flags + gen
  if (bid == 0) {
    for (int i = t; i < 2048; i += 256) gvec[i] = 0.f;  // 16 contention-spread copies
    if (t == 0) *done = 0u;
    for (int i = t; i < NBIN; i += 256) gCur[i] = 0u;
    if (wv == 0) {  // gb = gat_b . lin_W + lin_b, hoisted out of the gate stage
      float gb = wsum(gat_b[lane] * lin_W[lane]);
      if (lane == 0) *gbS = gb + lin_b[0];
    }
  }
  {  // x -> fp8 e4m3: thread handles node bid*16+(t>>4), dims (t&15)*8 .. +7
    int n = bid * 16 + (t >> 4);
    int dp = (t & 15) * 8;
    const float4* x4 = (const float4*)(x + n * 128 + dp);
    float4 a = x4[0], b = x4[1];
    unsigned p0 = f2fp8x2(a.x, a.y), p1 = f2fp8x2(a.z, a.w);
    unsigned p2 = f2fp8x2(b.x, b.y), p3 = f2fp8x2(b.z, b.w);
    ((uint2*)xbu)[n * 16 + (t & 15)] = make_uint2(p0 | (p1 << 16), p2 | (p3 << 16));
  }
  {
    float sa = 0.f, sd = 0.f, sz = 0.f;
#pragma unroll 8
    for (int k = 0; k < 64; k++) {
      float w = gw[t * 64 + k];
      sa += w * att_s[k]; sd += w * att_d[k]; sz += w * lin_W[k];
    }
    sm[t] = sa; sm[256 + t] = sd; sm[512 + t] = sz;
  }
  __syncthreads();
#pragma unroll
  for (int j = 0; j < 4; j++) {
    int n = bid * 16 + wv * 4 + j;
    float e0 = embed[n * 128 + lane], e1 = embed[n * 128 + 64 + lane];
    float pA = wsum(e0 * sm[lane] + e1 * sm[64 + lane]);
    float qA = wsum(e0 * sm[128 + lane] + e1 * sm[192 + lane]);
    float pD = wsum(e0 * sm[256 + lane] + e1 * sm[320 + lane]);
    float qD = wsum(e0 * sm[384 + lane] + e1 * sm[448 + lane]);
    float pZ = wsum(e0 * sm[512 + lane] + e1 * sm[576 + lane]);
    float qZ = wsum(e0 * sm[640 + lane] + e1 * sm[704 + lane]);
    if (lane == 0) pN[n] = make_float4(pA, pD, pZ, 0.f);
    if (lane == 1) qN[n] = make_float4(qA, qD, qZ, 0.f);
  }
}

// gather one node's aggregated features (fp8 rows = 128B, 4-wide ILP); returns f32 pair
__device__ __forceinline__ float2 gatherNode(const unsigned short* __restrict__ xb, int n, int lane,
                                             const int* __restrict__ colOffs,
                                             const unsigned* __restrict__ csrW) {
  float2 sf = fp8x2f(xb[n * 64 + lane]);
  float a0 = sf.x, a1 = sf.y, ws = 0.f;
  int off = colOffs[n], end = colOffs[n + 1];
  int i = off;
  for (; i + 4 <= end; i += 4) {
    unsigned q0 = csrW[i], q1 = csrW[i + 1], q2 = csrW[i + 2], q3 = csrW[i + 3];
    unsigned short u0 = xb[(q0 & 0x1fff) * 64 + lane];
    unsigned short u1 = xb[(q1 & 0x1fff) * 64 + lane];
    unsigned short u2 = xb[(q2 & 0x1fff) * 64 + lane];
    unsigned short u3 = xb[(q3 & 0x1fff) * 64 + lane];
    float w0 = bf1f(q0 >> 16), w1 = bf1f(q1 >> 16);
    float w2 = bf1f(q2 >> 16), w3 = bf1f(q3 >> 16);
    ws += w0 + w1 + w2 + w3;
    float2 f0 = fp8x2f(u0), f1 = fp8x2f(u1), f2v = fp8x2f(u2), f3 = fp8x2f(u3);
    a0 += w0 * f0.x + w1 * f1.x + w2 * f2v.x + w3 * f3.x;
    a1 += w0 * f0.y + w1 * f1.y + w2 * f2v.y + w3 * f3.y;
  }
  for (; i < end; i++) {
    unsigned q = csrW[i];
    unsigned short u = xb[(q & 0x1fff) * 64 + lane];
    float w = bf1f(q >> 16);
    ws += w;
    float2 f = fp8x2f(u);
    a0 += w * f.x;
    a1 += w * f.y;
  }
  float inv = 1.f / (1.f + ws);
  return make_float2(a0 * inv, a1 * inv);
}

// ---- GEMM: T in registers (lane L holds dims 2L,2L+1), W bf16 in 32KB LDS,
//      T[k] broadcast via scalar readlane ----
#define GEMM2(tv, acc)                                                   \
  {                                                                      \
    _Pragma("unroll") for (int j = 0; j < 2; j++) acc[j] = make_float2(0.f, 0.f); \
    _Pragma("unroll 16") for (int k2 = 0; k2 < 64; k2++) {               \
      float2 w0 = bf2f(Wl[(2 * k2) * 64 + lane]);                        \
      float2 w1 = bf2f(Wl[(2 * k2 + 1) * 64 + lane]);                    \
      _Pragma("unroll") for (int j = 0; j < 2; j++) {                    \
        float bx = rdlane(tv[j].x, k2);                                  \
        float by = rdlane(tv[j].y, k2);                                  \
        acc[j].x += bx * w0.x + by * w1.x;                               \
        acc[j].y += bx * w0.y + by * w1.y;                               \
      }                                                                  \
    }                                                                    \
  }

// GCN layer stage inside kMEGA: stage W into LDS, gather 2 nodes/wave, GEMM, fp8 out.
__device__ __forceinline__ void gcnStage(const unsigned short* __restrict__ xb,
                                         const float* __restrict__ W,
                                         unsigned* Wl,
                                         const int* __restrict__ colOffs,
                                         const unsigned* __restrict__ csrW,
                                         int bid, int t, int lane, int wv,
                                         unsigned short* __restrict__ outB) {
  const float4* W4 = (const float4*)W;
  for (int i = t; i < 4096; i += 256) {
    float4 a = W4[i];
    ((uint2*)Wl)[i] = make_uint2(f2bf(a.x, a.y), f2bf(a.z, a.w));
  }
  int nb = bid * 8;
  float2 tv[2];
#pragma unroll
  for (int j = 0; j < 2; j++)
    tv[j] = gatherNode(xb, nb + wv * 2 + j, lane, colOffs, csrW);
  __syncthreads();
  float2 acc[2];
  GEMM2(tv, acc)
#pragma unroll
  for (int j = 0; j < 2; j++) {
    int n = nb + wv * 2 + j;
    outB[n * 64 + lane] = f2fp8x2(fmaxf(acc[j].x, 0.f), fmaxf(acc[j].y, 0.f));
  }
}

// MEGA: [kB+kC | kD | kE | kF(W1) | kF(W2) | kH(W3)] with flag-tree grid barriers.
// 1024 blocks x 256 thr, 32KB LDS, <=128 VGPR => 4 blocks/CU co-resident.
__global__ __launch_bounds__(256, 4) void kMEGA(
    const int* __restrict__ row, const int* __restrict__ col,
    const float4* __restrict__ pN, const float4* __restrict__ qN,
    float2* __restrict__ asz, float* __restrict__ ad,
    int* __restrict__ colCnt,
    const int* __restrict__ src2, const int* __restrict__ dst2,
    unsigned* __restrict__ gCur, unsigned* __restrict__ bucket,
    const float* __restrict__ gbS, const float* __restrict__ noise,
    const float* __restrict__ tmp,
    int* __restrict__ hKeys, unsigned* __restrict__ hPair,
    int* __restrict__ eslot, int* __restrict__ colOffs, int* __restrict__ colCur,
    unsigned* __restrict__ csrW,
    const unsigned short* __restrict__ xbu,
    unsigned short* __restrict__ H1u, unsigned short* __restrict__ H2u,
    const float* __restrict__ W1, const float* __restrict__ W2,
    const float* __restrict__ W3, const float* __restrict__ Wc,
    float* __restrict__ gvec, unsigned* __restrict__ done,
    float* __restrict__ out, unsigned* __restrict__ barA) {
  __shared__ unsigned Wl[8192];  // 32KB union: hist/base/lcur | acc/adl/sd32 | W bf16
  int bid = blockIdx.x, t = threadIdx.x;
  int lane = t & 63, wv = t >> 6;

  // ---- S0: per-edge scalars + edge2 binning (blocks 0..319) ----
  if (bid < NBIN) {
    unsigned* hist = Wl;
    unsigned* base = Wl + NBIN;
    unsigned* lcur = Wl + 2 * NBIN;
    for (int i = t; i < NBIN; i += 256) { hist[i] = 0u; lcur[i] = 0u; }
    int blockBase = bid * 4096;
    {
      int e = bid * 256 + t;
      int r = row[e], c = col[e];
      float4 p = pN[r];
      float4 q = qN[c];
      asz[e] = make_float2(p.x + q.x, p.z + q.z);  // {a_s, z}
      ad[e] = p.y + q.y;
      atomicAdd(&colCnt[c], 1);
    }
    __syncthreads();
    int4 dv[4];
#pragma unroll
    for (int j = 0; j < 4; j++) {
      dv[j] = *(const int4*)&dst2[blockBase + j * 1024 + t * 4];
      atomicAdd(&hist[dv[j].x >> 8], 1u);
      atomicAdd(&hist[dv[j].y >> 8], 1u);
      atomicAdd(&hist[dv[j].z >> 8], 1u);
      atomicAdd(&hist[dv[j].w >> 8], 1u);
    }
    __syncthreads();
    for (int i = t; i < NBIN; i += 256)
      if (hist[i]) base[i] = atomicAdd(&gCur[i], hist[i]);
    __syncthreads();
#pragma unroll
    for (int j = 0; j < 4; j++) {
      int4 sv = *(const int4*)&src2[blockBase + j * 1024 + t * 4];
      int ss[4] = {sv.x, sv.y, sv.z, sv.w};
      int dd[4] = {dv[j].x, dv[j].y, dv[j].z, dv[j].w};
#pragma unroll
      for (int k = 0; k < 4; k++) {
        int s = ss[k], d = dd[k];
        int b = d >> 8;
        unsigned r = atomicAdd(&lcur[b], 1u);
        unsigned pos = base[b] + r;
        if (pos < BCAP) bucket[(size_t)b * BCAP + pos] = ((unsigned)(d & 255) << SBITS) | (unsigned)s;
      }
    }
  }
  gbar2(barA, 1u, bid, t);

  // ---- S1: per-bin reduce + gate + hash insert (0..319); colCnt scan (320) ----
  if (bid <= NBIN) {
    if (bid == NBIN) {  // scan block
      int* sd32 = (int*)(Wl + 768);
      int beg = t * 32;
      int s = 0;
#pragma unroll 8
      for (int i = 0; i < 32; i++) s += colCnt[beg + i];
      sd32[t] = s;
      __syncthreads();
      for (int o = 1; o < 256; o <<= 1) {
        int v = (t >= o) ? sd32[t - o] : 0;
        __syncthreads();
        sd32[t] += v;
        __syncthreads();
      }
      int run = (t == 0) ? 0 : sd32[t - 1];
      for (int i = 0; i < 32; i++) {
        colOffs[beg + i] = run;
        colCur[beg + i] = run;
        run += colCnt[beg + i];
      }
      if (t == 255) colOffs[NN] = run;
    } else {
      float* acc = (float*)Wl;          // 512 f32
      float* adl = (float*)Wl + 512;    // 256 f32
      acc[2 * t] = 0.f; acc[2 * t + 1] = 0.f; adl[t] = ad[bid * 256 + t];
      __syncthreads();
      int cnt = min((int)gCur[bid], BCAP);
      const unsigned* bp = bucket + (size_t)bid * BCAP;
      const unsigned SM = (1u << SBITS) - 1;
      int i = t;
      for (; i + 768 < cnt; i += 1024) {
        unsigned u0 = bp[i], u1 = bp[i + 256], u2 = bp[i + 512], u3 = bp[i + 768];
        float2 az0 = asz[u0 & SM], az1 = asz[u1 & SM], az2 = asz[u2 & SM], az3 = asz[u3 & SM];
        int l0 = u0 >> SBITS, l1 = u1 >> SBITS, l2 = u2 >> SBITS, l3 = u3 >> SBITS;
        float ea0 = __expf(lrelu(az0.x + adl[l0]));
        float ea1 = __expf(lrelu(az1.x + adl[l1]));
        float ea2 = __expf(lrelu(az2.x + adl[l2]));
        float ea3 = __expf(lrelu(az3.x + adl[l3]));
        atomicAdd(&acc[2 * l0], ea0); atomicAdd(&acc[2 * l0 + 1], ea0 * az0.y);
        atomicAdd(&acc[2 * l1], ea1); atomicAdd(&acc[2 * l1 + 1], ea1 * az1.y);
        atomicAdd(&acc[2 * l2], ea2); atomicAdd(&acc[2 * l2 + 1], ea2 * az2.y);
        atomicAdd(&acc[2 * l3], ea3); atomicAdd(&acc[2 * l3 + 1], ea3 * az3.y);
      }
      for (; i < cnt; i += 256) {
        unsigned u = bp[i];
        float2 az = asz[u & SM];
        int l = u >> SBITS;
        float ea = __expf(lrelu(az.x + adl[l]));
        atomicAdd(&acc[2 * l], ea);
        atomicAdd(&acc[2 * l + 1], ea * az.y);
      }
      __syncthreads();
      float gb = *gbS;
      float itmp = 1.f / tmp[0];
      {
        int e = bid * 256 + t;
        float2 szv = asz[e];
        float eself = __expf(lrelu(szv.x + adl[t]));  // softmax shift-invariant
        float la = (acc[2 * t + 1] + eself * szv.y) / (acc[2 * t] + eself) + gb;
        float ns = noise[e];
        float g = (logf(ns) - log1pf(-ns) + la) * itmp;
        float gate = 1.f / (1.f + __expf(-g));
        int key = row[e] * NN + col[e];
        unsigned hi = ((unsigned)key * 2654435761u) >> 14 & HMASK;
        while (true) {
          int old = atomicCAS(&hKeys[hi], -1, key);
          if (old == -1 || old == key) break;
          hi = (hi + 1) & HMASK;
        }
        eslot[e] = (int)hi;  // forward slot for the kE stage (skips its probe)
        atomic_pk_add_f16(&hPair[hi], packh2(1.0f, gate));
      }
    }
  }
  gbar2(barA, 2u, bid, t);

  // ---- S2: edge_mask -> w, CSR scatter (blocks 0..319) ----
  if (bid < NBIN) {
    int e = bid * 256 + t;
    int r = row[e], c = col[e];
    int s1 = eslot[e];
    unsigned u1 = hPair[s1];
    __half2 h1 = *reinterpret_cast<__half2*>(&u1);
    float cv = __low2float(h1), g1 = __high2float(h1);
    int s2 = hfind(hKeys, c * NN + r);
    float g2 = 0.f;
    if (s2 >= 0) {
      unsigned u2 = hPair[s2];
      g2 = __high2float(*reinterpret_cast<__half2*>(&u2));
    }
    float em = cv * 0.5f * (g1 + g2);
    float w = 1.f / (1.f + __expf(-em));
    int pos = atomicAdd(&colCur[c], 1);
    csrW[pos] = (f2bf1(w) << 16) | (unsigned)r;
  }
  gbar2(barA, 3u, bid, t);

  // ---- S3: GCN layer 1 ----
  gcnStage(xbu, W1, Wl, colOffs, csrW, bid, t, lane, wv, H1u);
  gbar2(barA, 4u, bid, t);

  // ---- S4: GCN layer 2 ----
  gcnStage(H1u, W2, Wl, colOffs, csrW, bid, t, lane, wv, H2u);
  gbar2(barA, 5u, bid, t);

  // ---- S5: layer 3 + pool + classifier (kH body) ----
  {
    const float4* W4 = (const float4*)W3;
    for (int i = t; i < 4096; i += 256) {
      float4 a = W4[i];
      ((uint2*)Wl)[i] = make_uint2(f2bf(a.x, a.y), f2bf(a.z, a.w));
    }
    int nb = bid * 8;
    float2 tv[2];
#pragma unroll
    for (int j = 0; j < 2; j++)
      tv[j] = gatherNode(H2u, nb + wv * 2 + j, lane, colOffs, csrW);
    __syncthreads();
    float2 acc[2];
    GEMM2(tv, acc)
    // pool: H3 never written to memory
    float s0 = fmaxf(acc[0].x, 0.f) + fmaxf(acc[1].x, 0.f);
    float s1 = fmaxf(acc[0].y, 0.f) + fmaxf(acc[1].y, 0.f);
    __syncthreads();  // GEMM done reading Wl; reuse as scratch
    float* gpart = (float*)Wl;
    unsigned* flagp = (unsigned*)Wl + 600;
    if (t < 128) gpart[t] = 0.f;
    __syncthreads();
    atomicAdd(&gpart[2 * lane], s0);
    atomicAdd(&gpart[2 * lane + 1], s1);
    __syncthreads();
    if (t < 128) atomicAdd(&gvec[((bid & 15) << 7) + t], gpart[t]);
    asm volatile("s_waitcnt vmcnt(0)" ::: "memory");  // gvec atomics complete (memory-side)
    __syncthreads();
    if (t == 0) *flagp = (atomicAdd(done, 1u) == (unsigned)(gridDim.x - 1)) ? 1u : 0u;
    __syncthreads();
    if (*flagp) {
      float* f0 = (float*)Wl + 256;
      float* f1 = (float*)Wl + 384;
      if (t < 128) {
        float gj = 0.f;
#pragma unroll
        for (int k = 0; k < 16; k++) gj += atomicAdd(&gvec[k * 128 + t], 0.f);  // memory-side reads
        gj *= (1.0f / 8192.0f);
        f0[t] = gj * Wc[t * 2 + 0];
        f1[t] = gj * Wc[t * 2 + 1];
      }
      __syncthreads();
      for (int o = 64; o > 0; o >>= 1) {
        if (t < o) { f0[t] += f0[t + o]; f1[t] += f1[t + o]; }
        __syncthreads();
      }
      if (t == 0) {
        float l0 = f0[0], l1 = f1[0];
        float m = fmaxf(l0, l1);
        float e0 = __expf(l0 - m), e1 = __expf(l1 - m);
        float inv = 1.f / (e0 + e1);
        out[0] = e0 * inv;
        out[1] = e1 * inv;
      }
    }
  }
}

extern "C" void kernel_launch(void* const* d_in, const int* in_sizes, int n_in,
                              void* d_out, int out_size, void* d_ws, size_t ws_size,
                              hipStream_t stream) {
  const float* x     = (const float*)d_in[0];
  const float* embed = (const float*)d_in[1];
  const float* noise = (const float*)d_in[2];
  const float* tmp   = (const float*)d_in[3];
  const float* gat_W = (const float*)d_in[4];
  const float* att_s = (const float*)d_in[5];
  const float* att_d = (const float*)d_in[6];
  const float* gat_b = (const float*)d_in[7];
  const float* lin_W = (const float*)d_in[8];
  const float* lin_b = (const float*)d_in[9];
  const float* W1    = (const float*)d_in[10];
  const float* W2    = (const float*)d_in[11];
  const float* W3    = (const float*)d_in[12];
  const float* Wc    = (const float*)d_in[13];
  const int* ei      = (const int*)d_in[14];
  const int* nei     = (const int*)d_in[15];
  const int* row = ei;
  const int* col = ei + EE;
  const int* src2 = nei;
  const int* dst2 = nei + E2C;
  float* out = (float*)d_out;

  // workspace layout (4-byte units); 16B/8B-aligned buffers first
  char* w8 = (char*)d_ws;
  size_t off = 0;
  auto alloc = [&](size_t units) -> void* {
    void* p = w8 + off * 4;
    off += units;
    return p;
  };
  float4*   pN      = (float4*)alloc(4 * NN);
  float4*   qN      = (float4*)alloc(4 * NN);
  float2*   asz     = (float2*)alloc(2 * EE);
  unsigned short* xbu = (unsigned short*)alloc(NN * 32);  // fp8x2 per lane
  unsigned short* H1u = (unsigned short*)alloc(NN * 32);
  unsigned short* H2u = (unsigned short*)alloc(NN * 32);
  unsigned* csrW    = (unsigned*)alloc(EE);
  float*    ad      = (float*)alloc(EE);
  int*      eslot   = (int*)alloc(EE);
  int*      colCnt  = (int*)alloc(NN);
  int*      colOffs = (int*)alloc(NN + 2);
  int*      colCur  = (int*)alloc(NN);
  int*      hKeys   = (int*)alloc(HSZ);
  unsigned* hPair   = (unsigned*)alloc(HSZ);
  unsigned* bucket  = (unsigned*)alloc((size_t)NBIN * BCAP);
  unsigned* gCur    = (unsigned*)alloc(NBIN);
  float*    gvec    = (float*)alloc(2048);  // 16 copies x 128
  unsigned* done    = (unsigned*)alloc(2);
  float*    gbS     = (float*)alloc(2);
  unsigned* barA    = (unsigned*)alloc(1152);  // arrive flags[1024] + pad + gen

  kA<<<512, 256, 0, stream>>>(x, embed, gat_W, att_s, att_d, lin_W, gat_b, lin_b,
                              pN, qN, xbu, hKeys, hPair, colCnt, gvec, done, gCur, gbS, barA);
  kMEGA<<<MBLK, 256, 0, stream>>>(row, col, pN, qN, asz, ad, colCnt, src2, dst2,
                                  gCur, bucket, gbS, noise, tmp, hKeys, hPair,
                                  eslot, colOffs, colCur, csrW, xbu, H1u, H2u,
                                  W1, W2, W3, Wc, gvec, done, out, barA);
}

// Round 6
// 236.726 us; speedup vs baseline: 5.0527x; 4.8206x over previous
//
#include <hip/hip_runtime.h>
#include <hip/hip_fp16.h>
#include <math.h>

typedef unsigned long long u64;
typedef __attribute__((ext_vector_type(2))) float fv2;

#define NN 8192
#define EE 81920
#define E2C 1310720
#define HSZ (1 << 18)
#define HMASK (HSZ - 1)
#define NBIN 320     // dst >> 8 : bins of 256 edge-nodes
#define BCAP 4800    // Poisson(4096), +11 sigma
#define SBITS 17     // src index bits in packed u32 payload
#define DCAP 40      // padded-CSR per-node capacity; Poisson(10), P(>=40)~1e-13

__device__ __forceinline__ float wsum(float v) {
#pragma unroll
  for (int m = 32; m > 0; m >>= 1) v += __shfl_xor(v, m, 64);
  return v;
}
__device__ __forceinline__ float lrelu(float x) { return x > 0.f ? x : 0.2f * x; }
__device__ __forceinline__ unsigned packh2(float a, float b) {
  __half2 h = __floats2half2_rn(a, b);
  return *reinterpret_cast<unsigned*>(&h);
}
__device__ __forceinline__ void atomic_pk_add_f16(unsigned* addr, unsigned data) {
  asm volatile("global_atomic_pk_add_f16 %0, %1, off" :: "v"(addr), "v"(data) : "memory");
}
__device__ __forceinline__ int hfind(const int* __restrict__ keys, int key) {
  unsigned i = ((unsigned)key * 2654435761u) >> 14 & HMASK;
  while (true) {
    int k = keys[i];
    if (k == key) return (int)i;
    if (k == -1) return -1;
    i = (i + 1) & HMASK;
  }
}
// bf16 helpers
__device__ __forceinline__ float2 bf2f(unsigned u) {
  return make_float2(__uint_as_float(u << 16), __uint_as_float(u & 0xffff0000u));
}
__device__ __forceinline__ unsigned f2bf(float a, float b) {
  unsigned ua = __float_as_uint(a);
  ua = (ua + 0x7fffu + ((ua >> 16) & 1u)) >> 16;
  unsigned ub = __float_as_uint(b);
  ub = ((ub + 0x7fffu + ((ub >> 16) & 1u)) >> 16) << 16;
  return (ua & 0xffffu) | ub;
}
__device__ __forceinline__ unsigned f2bf1(float a) {
  unsigned ua = __float_as_uint(a);
  return (ua + 0x7fffu + ((ua >> 16) & 1u)) >> 16;
}
__device__ __forceinline__ float bf1f(unsigned u) { return __uint_as_float(u << 16); }
// fp8 e4m3 pack/unpack (HW cvt, gfx950 OCP)
__device__ __forceinline__ unsigned short f2fp8x2(float a, float b) {
  return (unsigned short)(__builtin_amdgcn_cvt_pk_fp8_f32(a, b, 0, false) & 0xffff);
}
__device__ __forceinline__ float2 fp8x2f(unsigned short v) {
  fv2 f = __builtin_amdgcn_cvt_pk_f32_fp8((int)(unsigned)v, false);
  return make_float2(f[0], f[1]);
}
// wave-uniform broadcast of lane k's value via scalar readlane (no LDS traffic)
__device__ __forceinline__ float rdlane(float v, int k) {
  return __uint_as_float(__builtin_amdgcn_readlane(__float_as_uint(v), k));
}

// A: init + x->fp8 + per-block combo in LDS + node scalars + gb scalar. 512 blocks.
__global__ __launch_bounds__(256) void kA(const float* __restrict__ x,
                                          const float* __restrict__ embed,
                                          const float* __restrict__ gw,
                                          const float* __restrict__ att_s,
                                          const float* __restrict__ att_d,
                                          const float* __restrict__ lin_W,
                                          const float* __restrict__ gat_b,
                                          const float* __restrict__ lin_b,
                                          float4* __restrict__ pN, float4* __restrict__ qN,
                                          unsigned short* __restrict__ xbu,
                                          int* __restrict__ hKeys, unsigned* __restrict__ hPair,
                                          int* __restrict__ colCnt, float* __restrict__ gvec,
                                          unsigned* __restrict__ done, unsigned* __restrict__ gCur,
                                          float* __restrict__ gbS) {
  __shared__ float sm[768];  // cA | cD | cZ
  int t = threadIdx.x, bid = blockIdx.x;
  int lane = t & 63, wv = t >> 6;
  for (int i = bid * 256 + t; i < HSZ; i += 512 * 256) { hKeys[i] = -1; hPair[i] = 0u; }
  for (int i = bid * 256 + t; i < NN; i += 512 * 256) colCnt[i] = 0;
  if (bid == 0) {
    for (int i = t; i < 2048; i += 256) gvec[i] = 0.f;  // 16 contention-spread copies
    if (t == 0) *done = 0u;
    for (int i = t; i < NBIN; i += 256) gCur[i] = 0u;
    if (wv == 0) {  // gb = gat_b . lin_W + lin_b, hoisted out of the gate stage
      float gb = wsum(gat_b[lane] * lin_W[lane]);
      if (lane == 0) *gbS = gb + lin_b[0];
    }
  }
  {  // x -> fp8 e4m3: thread handles node bid*16+(t>>4), dims (t&15)*8 .. +7
    int n = bid * 16 + (t >> 4);
    int dp = (t & 15) * 8;
    const float4* x4 = (const float4*)(x + n * 128 + dp);
    float4 a = x4[0], b = x4[1];
    unsigned p0 = f2fp8x2(a.x, a.y), p1 = f2fp8x2(a.z, a.w);
    unsigned p2 = f2fp8x2(b.x, b.y), p3 = f2fp8x2(b.z, b.w);
    ((uint2*)xbu)[n * 16 + (t & 15)] = make_uint2(p0 | (p1 << 16), p2 | (p3 << 16));
  }
  {
    float sa = 0.f, sd = 0.f, sz = 0.f;
#pragma unroll 8
    for (int k = 0; k < 64; k++) {
      float w = gw[t * 64 + k];
      sa += w * att_s[k]; sd += w * att_d[k]; sz += w * lin_W[k];
    }
    sm[t] = sa; sm[256 + t] = sd; sm[512 + t] = sz;
  }
  __syncthreads();
#pragma unroll
  for (int j = 0; j < 4; j++) {
    int n = bid * 16 + wv * 4 + j;
    float e0 = embed[n * 128 + lane], e1 = embed[n * 128 + 64 + lane];
    float pA = wsum(e0 * sm[lane] + e1 * sm[64 + lane]);
    float qA = wsum(e0 * sm[128 + lane] + e1 * sm[192 + lane]);
    float pD = wsum(e0 * sm[256 + lane] + e1 * sm[320 + lane]);
    float qD = wsum(e0 * sm[384 + lane] + e1 * sm[448 + lane]);
    float pZ = wsum(e0 * sm[512 + lane] + e1 * sm[576 + lane]);
    float qZ = wsum(e0 * sm[640 + lane] + e1 * sm[704 + lane]);
    if (lane == 0) pN[n] = make_float4(pA, pD, pZ, 0.f);
    if (lane == 1) qN[n] = make_float4(qA, qD, qZ, 0.f);
  }
}

// C: 320 blocks. (1) per-edge scalars + padded-CSR edge-id scatter for its 256
// edges, (2) partition its 4096 edge2 entries into bins.
__global__ __launch_bounds__(256) void kC(const int* __restrict__ row, const int* __restrict__ col,
                                          const float4* __restrict__ pN, const float4* __restrict__ qN,
                                          float2* __restrict__ asz, float* __restrict__ ad,
                                          int* __restrict__ colCnt, int* __restrict__ csrE,
                                          const int* __restrict__ src2, const int* __restrict__ dst2,
                                          unsigned* __restrict__ gCur, unsigned* __restrict__ bucket) {
  __shared__ unsigned hist[NBIN], base[NBIN], lcur[NBIN];
  int t = threadIdx.x;
  for (int i = t; i < NBIN; i += 256) { hist[i] = 0u; lcur[i] = 0u; }
  int blockBase = blockIdx.x * 4096;
  {
    int e = blockIdx.x * 256 + t;
    int r = row[e], c = col[e];
    float4 p = pN[r];
    float4 q = qN[c];
    asz[e] = make_float2(p.x + q.x, p.z + q.z);  // {a_s, z}
    ad[e] = p.y + q.y;
    int s = atomicAdd(&colCnt[c], 1);
    if (s < DCAP) csrE[c * DCAP + s] = e;  // padded CSR: no scan, no colCur
  }
  __syncthreads();
  int4 dv[4];
#pragma unroll
  for (int j = 0; j < 4; j++) {
    dv[j] = *(const int4*)&dst2[blockBase + j * 1024 + t * 4];
    atomicAdd(&hist[dv[j].x >> 8], 1u);
    atomicAdd(&hist[dv[j].y >> 8], 1u);
    atomicAdd(&hist[dv[j].z >> 8], 1u);
    atomicAdd(&hist[dv[j].w >> 8], 1u);
  }
  __syncthreads();
  for (int i = t; i < NBIN; i += 256)
    if (hist[i]) base[i] = atomicAdd(&gCur[i], hist[i]);
  __syncthreads();
#pragma unroll
  for (int j = 0; j < 4; j++) {
    int4 sv = *(const int4*)&src2[blockBase + j * 1024 + t * 4];
    int ss[4] = {sv.x, sv.y, sv.z, sv.w};
    int dd[4] = {dv[j].x, dv[j].y, dv[j].z, dv[j].w};
#pragma unroll
    for (int k = 0; k < 4; k++) {
      int s = ss[k], d = dd[k];
      int b = d >> 8;
      unsigned r = atomicAdd(&lcur[b], 1u);
      unsigned pos = base[b] + r;
      if (pos < BCAP) bucket[(size_t)b * BCAP + pos] = ((unsigned)(d & 255) << SBITS) | (unsigned)s;
    }
  }
}

// D: 320 blocks. Per-bin reduce + gate + hash insert (records slot in eslot).
__global__ __launch_bounds__(256) void kD(const int* __restrict__ row, const int* __restrict__ col,
                                          const float2* __restrict__ asz, const float* __restrict__ ad,
                                          const unsigned* __restrict__ bucket, const unsigned* __restrict__ gCur,
                                          const float* __restrict__ gbS,
                                          const float* __restrict__ noise,
                                          const float* __restrict__ tmp,
                                          int* __restrict__ hKeys, unsigned* __restrict__ hPair,
                                          int* __restrict__ eslot) {
  __shared__ float acc[512];
  __shared__ float adl[256];
  int b = blockIdx.x, t = threadIdx.x;
  acc[2 * t] = 0.f; acc[2 * t + 1] = 0.f; adl[t] = ad[b * 256 + t];
  __syncthreads();
  int cnt = min((int)gCur[b], BCAP);
  const unsigned* bp = bucket + (size_t)b * BCAP;
  const unsigned SM = (1u << SBITS) - 1;
  int i = t;
  for (; i + 768 < cnt; i += 1024) {
    unsigned u0 = bp[i], u1 = bp[i + 256], u2 = bp[i + 512], u3 = bp[i + 768];
    float2 az0 = asz[u0 & SM], az1 = asz[u1 & SM], az2 = asz[u2 & SM], az3 = asz[u3 & SM];
    int l0 = u0 >> SBITS, l1 = u1 >> SBITS, l2 = u2 >> SBITS, l3 = u3 >> SBITS;
    float ea0 = __expf(lrelu(az0.x + adl[l0]));
    float ea1 = __expf(lrelu(az1.x + adl[l1]));
    float ea2 = __expf(lrelu(az2.x + adl[l2]));
    float ea3 = __expf(lrelu(az3.x + adl[l3]));
    atomicAdd(&acc[2 * l0], ea0); atomicAdd(&acc[2 * l0 + 1], ea0 * az0.y);
    atomicAdd(&acc[2 * l1], ea1); atomicAdd(&acc[2 * l1 + 1], ea1 * az1.y);
    atomicAdd(&acc[2 * l2], ea2); atomicAdd(&acc[2 * l2 + 1], ea2 * az2.y);
    atomicAdd(&acc[2 * l3], ea3); atomicAdd(&acc[2 * l3 + 1], ea3 * az3.y);
  }
  for (; i < cnt; i += 256) {
    unsigned u = bp[i];
    float2 az = asz[u & SM];
    int l = u >> SBITS;
    float ea = __expf(lrelu(az.x + adl[l]));
    atomicAdd(&acc[2 * l], ea);
    atomicAdd(&acc[2 * l + 1], ea * az.y);
  }
  __syncthreads();
  float gb = *gbS;
  float itmp = 1.f / tmp[0];
  {
    int e = b * 256 + t;
    float2 szv = asz[e];
    float eself = __expf(lrelu(szv.x + adl[t]));  // softmax shift-invariant
    float la = (acc[2 * t + 1] + eself * szv.y) / (acc[2 * t] + eself) + gb;
    float ns = noise[e];
    float g = (logf(ns) - log1pf(-ns) + la) * itmp;
    float gate = 1.f / (1.f + __expf(-g));
    int key = row[e] * NN + col[e];
    unsigned hi = ((unsigned)key * 2654435761u) >> 14 & HMASK;
    while (true) {
      int old = atomicCAS(&hKeys[hi], -1, key);
      if (old == -1 || old == key) break;
      hi = (hi + 1) & HMASK;
    }
    eslot[e] = (int)hi;  // forward slot for the layer-1 fold (skips its probe)
    atomic_pk_add_f16(&hPair[hi], packh2(1.0f, gate));
  }
}

// edge-mask -> w for one edge (wave-uniform; loads broadcast). Verbatim kE math.
__device__ __forceinline__ float wfold(int n, int e, const int* __restrict__ row,
                                       const int* __restrict__ eslot,
                                       const unsigned* __restrict__ hPair,
                                       const int* __restrict__ hKeys, int& rOut) {
  int r = row[e];
  rOut = r;
  unsigned u1 = hPair[eslot[e]];
  __half2 h1 = *reinterpret_cast<__half2*>(&u1);
  float cv = __low2float(h1), g1 = __high2float(h1);
  int s2 = hfind(hKeys, n * NN + r);  // reverse edge (col*NN + row), col==n here
  float g2 = 0.f;
  if (s2 >= 0) {
    unsigned u2 = hPair[s2];
    g2 = __high2float(*reinterpret_cast<__half2*>(&u2));
  }
  float em = cv * 0.5f * (g1 + g2);
  return 1.f / (1.f + __expf(-em));
}

// layer-1 gather: padded CSR of edge ids, computes w on the fly (2-wide ILP on
// the hash chains) and caches (w_bf16|row) into csrW for layers 2/3.
__device__ __forceinline__ float2 gatherFold(const unsigned short* __restrict__ xb, int n, int lane,
                                             const int* __restrict__ cnt,
                                             const int* __restrict__ csrE,
                                             const int* __restrict__ row,
                                             const int* __restrict__ eslot,
                                             const unsigned* __restrict__ hPair,
                                             const int* __restrict__ hKeys,
                                             unsigned* __restrict__ csrW) {
  float2 sf = fp8x2f(xb[n * 64 + lane]);
  float a0 = sf.x, a1 = sf.y, ws = 0.f;
  int deg = min(cnt[n], DCAP);
  const int* seg = csrE + n * DCAP;
  unsigned* wseg = csrW + n * DCAP;
  int j = 0;
  for (; j + 2 <= deg; j += 2) {
    int e0 = seg[j], e1 = seg[j + 1];
    int r0, r1;
    float w0 = wfold(n, e0, row, eslot, hPair, hKeys, r0);
    float w1 = wfold(n, e1, row, eslot, hPair, hKeys, r1);
    if (lane == 0) {
      wseg[j] = (f2bf1(w0) << 16) | (unsigned)r0;
      wseg[j + 1] = (f2bf1(w1) << 16) | (unsigned)r1;
    }
    ws += w0 + w1;
    float2 f0 = fp8x2f(xb[r0 * 64 + lane]);
    float2 f1 = fp8x2f(xb[r1 * 64 + lane]);
    a0 += w0 * f0.x + w1 * f1.x;
    a1 += w0 * f0.y + w1 * f1.y;
  }
  for (; j < deg; j++) {
    int e = seg[j];
    int r;
    float w = wfold(n, e, row, eslot, hPair, hKeys, r);
    if (lane == 0) wseg[j] = (f2bf1(w) << 16) | (unsigned)r;
    ws += w;
    float2 f = fp8x2f(xb[r * 64 + lane]);
    a0 += w * f.x;
    a1 += w * f.y;
  }
  float inv = 1.f / (1.f + ws);
  return make_float2(a0 * inv, a1 * inv);
}

// layers 2/3 gather: padded csrW (w_bf16|row), 4-wide ILP.
__device__ __forceinline__ float2 gatherNodeP(const unsigned short* __restrict__ xb, int n, int lane,
                                              const int* __restrict__ cnt,
                                              const unsigned* __restrict__ csrW) {
  float2 sf = fp8x2f(xb[n * 64 + lane]);
  float a0 = sf.x, a1 = sf.y, ws = 0.f;
  int deg = min(cnt[n], DCAP);
  const unsigned* seg = csrW + n * DCAP;
  int i = 0;
  for (; i + 4 <= deg; i += 4) {
    unsigned q0 = seg[i], q1 = seg[i + 1], q2 = seg[i + 2], q3 = seg[i + 3];
    unsigned short u0 = xb[(q0 & 0x1fff) * 64 + lane];
    unsigned short u1 = xb[(q1 & 0x1fff) * 64 + lane];
    unsigned short u2 = xb[(q2 & 0x1fff) * 64 + lane];
    unsigned short u3 = xb[(q3 & 0x1fff) * 64 + lane];
    float w0 = bf1f(q0 >> 16), w1 = bf1f(q1 >> 16);
    float w2 = bf1f(q2 >> 16), w3 = bf1f(q3 >> 16);
    ws += w0 + w1 + w2 + w3;
    float2 f0 = fp8x2f(u0), f1 = fp8x2f(u1), f2v = fp8x2f(u2), f3 = fp8x2f(u3);
    a0 += w0 * f0.x + w1 * f1.x + w2 * f2v.x + w3 * f3.x;
    a1 += w0 * f0.y + w1 * f1.y + w2 * f2v.y + w3 * f3.y;
  }
  for (; i < deg; i++) {
    unsigned q = seg[i];
    unsigned short u = xb[(q & 0x1fff) * 64 + lane];
    float w = bf1f(q >> 16);
    ws += w;
    float2 f = fp8x2f(u);
    a0 += w * f.x;
    a1 += w * f.y;
  }
  float inv = 1.f / (1.f + ws);
  return make_float2(a0 * inv, a1 * inv);
}

// ---- GEMM: T in registers (lane L holds dims 2L,2L+1), W bf16 in 32KB LDS,
//      T[k] broadcast via scalar readlane ----
#define GEMM2(tv, acc)                                                   \
  {                                                                      \
    _Pragma("unroll") for (int j = 0; j < 2; j++) acc[j] = make_float2(0.f, 0.f); \
    _Pragma("unroll 16") for (int k2 = 0; k2 < 64; k2++) {               \
      float2 w0 = bf2f(Wl[(2 * k2) * 64 + lane]);                        \
      float2 w1 = bf2f(Wl[(2 * k2 + 1) * 64 + lane]);                    \
      _Pragma("unroll") for (int j = 0; j < 2; j++) {                    \
        float bx = rdlane(tv[j].x, k2);                                  \
        float by = rdlane(tv[j].y, k2);                                  \
        acc[j].x += bx * w0.x + by * w1.x;                               \
        acc[j].y += bx * w0.y + by * w1.y;                               \
      }                                                                  \
    }                                                                    \
  }

// F1: GCN layer 1 with inline edge-mask fold (kE absorbed). 8 nodes/block.
__global__ __launch_bounds__(256) void kF1(const unsigned short* __restrict__ xb,
                                           const int* __restrict__ colCnt,
                                           const int* __restrict__ csrE,
                                           const int* __restrict__ row,
                                           const int* __restrict__ eslot,
                                           const unsigned* __restrict__ hPair,
                                           const int* __restrict__ hKeys,
                                           unsigned* __restrict__ csrW,
                                           const float* __restrict__ W,
                                           unsigned short* __restrict__ outB) {
  __shared__ unsigned Wl[128 * 64];  // bf16x2: Wl[k*64+l] = W[k][2l..2l+1]
  int t = threadIdx.x, lane = t & 63, wv = t >> 6;
  const float4* W4 = (const float4*)W;
  for (int i = t; i < 4096; i += 256) {
    float4 a = W4[i];
    ((uint2*)Wl)[i] = make_uint2(f2bf(a.x, a.y), f2bf(a.z, a.w));
  }
  int nb = blockIdx.x * 8;
  float2 tv[2];
#pragma unroll
  for (int j = 0; j < 2; j++)
    tv[j] = gatherFold(xb, nb + wv * 2 + j, lane, colCnt, csrE, row, eslot, hPair, hKeys, csrW);
  __syncthreads();
  float2 acc[2];
  GEMM2(tv, acc)
#pragma unroll
  for (int j = 0; j < 2; j++) {
    int n = nb + wv * 2 + j;
    outB[n * 64 + lane] = f2fp8x2(fmaxf(acc[j].x, 0.f), fmaxf(acc[j].y, 0.f));
  }
}

// F: GCN layer 2, padded-CSR gather. 8 nodes/block.
__global__ __launch_bounds__(256) void kF(const unsigned short* __restrict__ xb,
                                          const int* __restrict__ colCnt,
                                          const unsigned* __restrict__ csrW,
                                          const float* __restrict__ W,
                                          unsigned short* __restrict__ outB) {
  __shared__ unsigned Wl[128 * 64];
  int t = threadIdx.x, lane = t & 63, wv = t >> 6;
  const float4* W4 = (const float4*)W;
  for (int i = t; i < 4096; i += 256) {
    float4 a = W4[i];
    ((uint2*)Wl)[i] = make_uint2(f2bf(a.x, a.y), f2bf(a.z, a.w));
  }
  int nb = blockIdx.x * 8;
  float2 tv[2];
#pragma unroll
  for (int j = 0; j < 2; j++)
    tv[j] = gatherNodeP(xb, nb + wv * 2 + j, lane, colCnt, csrW);
  __syncthreads();
  float2 acc[2];
  GEMM2(tv, acc)
#pragma unroll
  for (int j = 0; j < 2; j++) {
    int n = nb + wv * 2 + j;
    outB[n * 64 + lane] = f2fp8x2(fmaxf(acc[j].x, 0.f), fmaxf(acc[j].y, 0.f));
  }
}

// H: layer3 + pool + final. Pool accumulation spread over 16 gvec copies.
__global__ __launch_bounds__(256) void kH(const unsigned short* __restrict__ xb,
                                          const int* __restrict__ colCnt,
                                          const unsigned* __restrict__ csrW,
                                          const float* __restrict__ W,
                                          const float* __restrict__ Wc,
                                          float* __restrict__ gvec, unsigned* __restrict__ done,
                                          float* __restrict__ out) {
  __shared__ unsigned Wl[128 * 64];
  int t = threadIdx.x, lane = t & 63, wv = t >> 6;
  const float4* W4 = (const float4*)W;
  for (int i = t; i < 4096; i += 256) {
    float4 a = W4[i];
    ((uint2*)Wl)[i] = make_uint2(f2bf(a.x, a.y), f2bf(a.z, a.w));
  }
  int nb = blockIdx.x * 8;
  float2 tv[2];
#pragma unroll
  for (int j = 0; j < 2; j++)
    tv[j] = gatherNodeP(xb, nb + wv * 2 + j, lane, colCnt, csrW);
  __syncthreads();
  float2 acc[2];
  GEMM2(tv, acc)
  // pool: H3 never written to memory
  float s0 = fmaxf(acc[0].x, 0.f) + fmaxf(acc[1].x, 0.f);
  float s1 = fmaxf(acc[0].y, 0.f) + fmaxf(acc[1].y, 0.f);
  __syncthreads();  // GEMM done reading Wl; reuse as scratch
  float* gpart = (float*)Wl;
  unsigned* flagp = (unsigned*)Wl + 600;
  if (t < 128) gpart[t] = 0.f;
  __syncthreads();
  atomicAdd(&gpart[2 * lane], s0);
  atomicAdd(&gpart[2 * lane + 1], s1);
  __syncthreads();
  if (t < 128) atomicAdd(&gvec[((blockIdx.x & 15) << 7) + t], gpart[t]);
  asm volatile("s_waitcnt vmcnt(0)" ::: "memory");  // gvec atomics complete (memory-side)
  __syncthreads();
  if (t == 0) *flagp = (atomicAdd(done, 1u) == gridDim.x - 1) ? 1u : 0u;
  __syncthreads();
  if (*flagp) {
    float* f0 = (float*)Wl + 256;
    float* f1 = (float*)Wl + 384;
    if (t < 128) {
      float gj = 0.f;
#pragma unroll
      for (int k = 0; k < 16; k++) gj += atomicAdd(&gvec[k * 128 + t], 0.f);  // memory-side reads
      gj *= (1.0f / 8192.0f);
      f0[t] = gj * Wc[t * 2 + 0];
      f1[t] = gj * Wc[t * 2 + 1];
    }
    __syncthreads();
    for (int o = 64; o > 0; o >>= 1) {
      if (t < o) { f0[t] += f0[t + o]; f1[t] += f1[t + o]; }
      __syncthreads();
    }
    if (t == 0) {
      float l0 = f0[0], l1 = f1[0];
      float m = fmaxf(l0, l1);
      float e0 = __expf(l0 - m), e1 = __expf(l1 - m);
      float inv = 1.f / (e0 + e1);
      out[0] = e0 * inv;
      out[1] = e1 * inv;
    }
  }
}

extern "C" void kernel_launch(void* const* d_in, const int* in_sizes, int n_in,
                              void* d_out, int out_size, void* d_ws, size_t ws_size,
                              hipStream_t stream) {
  const float* x     = (const float*)d_in[0];
  const float* embed = (const float*)d_in[1];
  const float* noise = (const float*)d_in[2];
  const float* tmp   = (const float*)d_in[3];
  const float* gat_W = (const float*)d_in[4];
  const float* att_s = (const float*)d_in[5];
  const float* att_d = (const float*)d_in[6];
  const float* gat_b = (const float*)d_in[7];
  const float* lin_W = (const float*)d_in[8];
  const float* lin_b = (const float*)d_in[9];
  const float* W1    = (const float*)d_in[10];
  const float* W2    = (const float*)d_in[11];
  const float* W3    = (const float*)d_in[12];
  const float* Wc    = (const float*)d_in[13];
  const int* ei      = (const int*)d_in[14];
  const int* nei     = (const int*)d_in[15];
  const int* row = ei;
  const int* col = ei + EE;
  const int* src2 = nei;
  const int* dst2 = nei + E2C;
  float* out = (float*)d_out;

  // workspace layout (4-byte units); 16B/8B-aligned buffers first
  char* w8 = (char*)d_ws;
  size_t off = 0;
  auto alloc = [&](size_t units) -> void* {
    void* p = w8 + off * 4;
    off += units;
    return p;
  };
  float4*   pN      = (float4*)alloc(4 * NN);
  float4*   qN      = (float4*)alloc(4 * NN);
  float2*   asz     = (float2*)alloc(2 * EE);
  unsigned short* xbu = (unsigned short*)alloc(NN * 32);  // fp8x2 per lane
  unsigned short* H1u = (unsigned short*)alloc(NN * 32);
  unsigned short* H2u = (unsigned short*)alloc(NN * 32);
  unsigned* csrW    = (unsigned*)alloc(NN * DCAP);  // padded (w_bf16|row)
  int*      csrE    = (int*)alloc(NN * DCAP);       // padded edge ids
  float*    ad      = (float*)alloc(EE);
  int*      eslot   = (int*)alloc(EE);
  int*      colCnt  = (int*)alloc(NN);
  int*      hKeys   = (int*)alloc(HSZ);
  unsigned* hPair   = (unsigned*)alloc(HSZ);
  unsigned* bucket  = (unsigned*)alloc((size_t)NBIN * BCAP);
  unsigned* gCur    = (unsigned*)alloc(NBIN);
  float*    gvec    = (float*)alloc(2048);  // 16 copies x 128
  unsigned* done    = (unsigned*)alloc(2);
  float*    gbS     = (float*)alloc(2);

  kA<<<512, 256, 0, stream>>>(x, embed, gat_W, att_s, att_d, lin_W, gat_b, lin_b,
                              pN, qN, xbu, hKeys, hPair, colCnt, gvec, done, gCur, gbS);
  kC<<<NBIN, 256, 0, stream>>>(row, col, pN, qN, asz, ad, colCnt, csrE, src2, dst2, gCur, bucket);
  kD<<<NBIN, 256, 0, stream>>>(row, col, asz, ad, bucket, gCur, gbS, noise, tmp,
                               hKeys, hPair, eslot);
  kF1<<<NN / 8, 256, 0, stream>>>(xbu, colCnt, csrE, row, eslot, hPair, hKeys, csrW, W1, H1u);
  kF<<<NN / 8, 256, 0, stream>>>(H1u, colCnt, csrW, W2, H2u);
  kH<<<NN / 8, 256, 0, stream>>>(H2u, colCnt, csrW, W3, Wc, gvec, done, out);
}

// Round 7
// 212.956 us; speedup vs baseline: 5.6167x; 1.1116x over previous
//
#include <hip/hip_runtime.h>
#include <hip/hip_fp16.h>
#include <math.h>

typedef unsigned long long u64;
typedef __attribute__((ext_vector_type(2))) float fv2;

#define NN 8192
#define EE 81920
#define E2C 1310720
#define HSZ (1 << 18)
#define HMASK (HSZ - 1)
#define NBIN 320     // dst >> 8 : bins of 256 edge-nodes
#define BCAP 4800    // Poisson(4096), +11 sigma
#define SBITS 17     // src index bits in packed u32 payload
#define DCAP 40      // padded-CSR per-node capacity; Poisson(10), P(>=40)~1e-13

__device__ __forceinline__ float wsum(float v) {
#pragma unroll
  for (int m = 32; m > 0; m >>= 1) v += __shfl_xor(v, m, 64);
  return v;
}
__device__ __forceinline__ float lrelu(float x) { return x > 0.f ? x : 0.2f * x; }
__device__ __forceinline__ unsigned packh2(float a, float b) {
  __half2 h = __floats2half2_rn(a, b);
  return *reinterpret_cast<unsigned*>(&h);
}
__device__ __forceinline__ void atomic_pk_add_f16(unsigned* addr, unsigned data) {
  asm volatile("global_atomic_pk_add_f16 %0, %1, off" :: "v"(addr), "v"(data) : "memory");
}
__device__ __forceinline__ int hfind(const int* __restrict__ keys, int key) {
  unsigned i = ((unsigned)key * 2654435761u) >> 14 & HMASK;
  while (true) {
    int k = keys[i];
    if (k == key) return (int)i;
    if (k == -1) return -1;
    i = (i + 1) & HMASK;
  }
}
// bf16 helpers
__device__ __forceinline__ float2 bf2f(unsigned u) {
  return make_float2(__uint_as_float(u << 16), __uint_as_float(u & 0xffff0000u));
}
__device__ __forceinline__ unsigned f2bf(float a, float b) {
  unsigned ua = __float_as_uint(a);
  ua = (ua + 0x7fffu + ((ua >> 16) & 1u)) >> 16;
  unsigned ub = __float_as_uint(b);
  ub = ((ub + 0x7fffu + ((ub >> 16) & 1u)) >> 16) << 16;
  return (ua & 0xffffu) | ub;
}
__device__ __forceinline__ unsigned f2bf1(float a) {
  unsigned ua = __float_as_uint(a);
  return (ua + 0x7fffu + ((ua >> 16) & 1u)) >> 16;
}
__device__ __forceinline__ float bf1f(unsigned u) { return __uint_as_float(u << 16); }
// fp8 e4m3 pack/unpack (HW cvt, gfx950 OCP)
__device__ __forceinline__ unsigned short f2fp8x2(float a, float b) {
  return (unsigned short)(__builtin_amdgcn_cvt_pk_fp8_f32(a, b, 0, false) & 0xffff);
}
__device__ __forceinline__ float2 fp8x2f(unsigned short v) {
  fv2 f = __builtin_amdgcn_cvt_pk_f32_fp8((int)(unsigned)v, false);
  return make_float2(f[0], f[1]);
}
// wave-uniform broadcast of lane k's value via scalar readlane (no LDS traffic)
__device__ __forceinline__ float rdlane(float v, int k) {
  return __uint_as_float(__builtin_amdgcn_readlane(__float_as_uint(v), k));
}

// A: init + x->fp8 + per-block combo in LDS + node scalars + gb scalar. 512 blocks.
__global__ __launch_bounds__(256) void kA(const float* __restrict__ x,
                                          const float* __restrict__ embed,
                                          const float* __restrict__ gw,
                                          const float* __restrict__ att_s,
                                          const float* __restrict__ att_d,
                                          const float* __restrict__ lin_W,
                                          const float* __restrict__ gat_b,
                                          const float* __restrict__ lin_b,
                                          float4* __restrict__ pN, float4* __restrict__ qN,
                                          unsigned short* __restrict__ xbu,
                                          int* __restrict__ hKeys, unsigned* __restrict__ hPair,
                                          int* __restrict__ colCnt, float* __restrict__ gvec,
                                          unsigned* __restrict__ done, unsigned* __restrict__ gCur,
                                          float* __restrict__ gbS) {
  __shared__ float sm[768];  // cA | cD | cZ
  int t = threadIdx.x, bid = blockIdx.x;
  int lane = t & 63, wv = t >> 6;
  for (int i = bid * 256 + t; i < HSZ; i += 512 * 256) { hKeys[i] = -1; hPair[i] = 0u; }
  for (int i = bid * 256 + t; i < NN; i += 512 * 256) colCnt[i] = 0;
  if (bid == 0) {
    for (int i = t; i < 2048; i += 256) gvec[i] = 0.f;  // 16 contention-spread copies
    if (t == 0) *done = 0u;
    for (int i = t; i < NBIN; i += 256) gCur[i] = 0u;
    if (wv == 0) {  // gb = gat_b . lin_W + lin_b, hoisted out of the gate stage
      float gb = wsum(gat_b[lane] * lin_W[lane]);
      if (lane == 0) *gbS = gb + lin_b[0];
    }
  }
  {  // x -> fp8 e4m3: thread handles node bid*16+(t>>4), dims (t&15)*8 .. +7
    int n = bid * 16 + (t >> 4);
    int dp = (t & 15) * 8;
    const float4* x4 = (const float4*)(x + n * 128 + dp);
    float4 a = x4[0], b = x4[1];
    unsigned p0 = f2fp8x2(a.x, a.y), p1 = f2fp8x2(a.z, a.w);
    unsigned p2 = f2fp8x2(b.x, b.y), p3 = f2fp8x2(b.z, b.w);
    ((uint2*)xbu)[n * 16 + (t & 15)] = make_uint2(p0 | (p1 << 16), p2 | (p3 << 16));
  }
  {
    float sa = 0.f, sd = 0.f, sz = 0.f;
#pragma unroll 8
    for (int k = 0; k < 64; k++) {
      float w = gw[t * 64 + k];
      sa += w * att_s[k]; sd += w * att_d[k]; sz += w * lin_W[k];
    }
    sm[t] = sa; sm[256 + t] = sd; sm[512 + t] = sz;
  }
  __syncthreads();
#pragma unroll
  for (int j = 0; j < 4; j++) {
    int n = bid * 16 + wv * 4 + j;
    float e0 = embed[n * 128 + lane], e1 = embed[n * 128 + 64 + lane];
    float pA = wsum(e0 * sm[lane] + e1 * sm[64 + lane]);
    float qA = wsum(e0 * sm[128 + lane] + e1 * sm[192 + lane]);
    float pD = wsum(e0 * sm[256 + lane] + e1 * sm[320 + lane]);
    float qD = wsum(e0 * sm[384 + lane] + e1 * sm[448 + lane]);
    float pZ = wsum(e0 * sm[512 + lane] + e1 * sm[576 + lane]);
    float qZ = wsum(e0 * sm[640 + lane] + e1 * sm[704 + lane]);
    if (lane == 0) pN[n] = make_float4(pA, pD, pZ, 0.f);
    if (lane == 1) qN[n] = make_float4(qA, qD, qZ, 0.f);
  }
}

// C: 320 blocks. (1) per-edge scalars + padded-CSR edge-id scatter for its 256
// edges, (2) partition its 4096 edge2 entries into bins.
__global__ __launch_bounds__(256) void kC(const int* __restrict__ row, const int* __restrict__ col,
                                          const float4* __restrict__ pN, const float4* __restrict__ qN,
                                          float2* __restrict__ asz, float* __restrict__ ad,
                                          int* __restrict__ colCnt, int* __restrict__ csrE,
                                          const int* __restrict__ src2, const int* __restrict__ dst2,
                                          unsigned* __restrict__ gCur, unsigned* __restrict__ bucket) {
  __shared__ unsigned hist[NBIN], base[NBIN], lcur[NBIN];
  int t = threadIdx.x;
  for (int i = t; i < NBIN; i += 256) { hist[i] = 0u; lcur[i] = 0u; }
  int blockBase = blockIdx.x * 4096;
  {
    int e = blockIdx.x * 256 + t;
    int r = row[e], c = col[e];
    float4 p = pN[r];
    float4 q = qN[c];
    asz[e] = make_float2(p.x + q.x, p.z + q.z);  // {a_s, z}
    ad[e] = p.y + q.y;
    int s = atomicAdd(&colCnt[c], 1);
    if (s < DCAP) csrE[c * DCAP + s] = e;  // padded CSR: no scan, no colCur
  }
  __syncthreads();
  int4 dv[4];
#pragma unroll
  for (int j = 0; j < 4; j++) {
    dv[j] = *(const int4*)&dst2[blockBase + j * 1024 + t * 4];
    atomicAdd(&hist[dv[j].x >> 8], 1u);
    atomicAdd(&hist[dv[j].y >> 8], 1u);
    atomicAdd(&hist[dv[j].z >> 8], 1u);
    atomicAdd(&hist[dv[j].w >> 8], 1u);
  }
  __syncthreads();
  for (int i = t; i < NBIN; i += 256)
    if (hist[i]) base[i] = atomicAdd(&gCur[i], hist[i]);
  __syncthreads();
#pragma unroll
  for (int j = 0; j < 4; j++) {
    int4 sv = *(const int4*)&src2[blockBase + j * 1024 + t * 4];
    int ss[4] = {sv.x, sv.y, sv.z, sv.w};
    int dd[4] = {dv[j].x, dv[j].y, dv[j].z, dv[j].w};
#pragma unroll
    for (int k = 0; k < 4; k++) {
      int s = ss[k], d = dd[k];
      int b = d >> 8;
      unsigned r = atomicAdd(&lcur[b], 1u);
      unsigned pos = base[b] + r;
      if (pos < BCAP) bucket[(size_t)b * BCAP + pos] = ((unsigned)(d & 255) << SBITS) | (unsigned)s;
    }
  }
}

// D: 320 blocks. Per-bin reduce + gate + hash insert (records slot in eslot).
__global__ __launch_bounds__(256) void kD(const int* __restrict__ row, const int* __restrict__ col,
                                          const float2* __restrict__ asz, const float* __restrict__ ad,
                                          const unsigned* __restrict__ bucket, const unsigned* __restrict__ gCur,
                                          const float* __restrict__ gbS,
                                          const float* __restrict__ noise,
                                          const float* __restrict__ tmp,
                                          int* __restrict__ hKeys, unsigned* __restrict__ hPair,
                                          int* __restrict__ eslot) {
  __shared__ float acc[512];
  __shared__ float adl[256];
  int b = blockIdx.x, t = threadIdx.x;
  acc[2 * t] = 0.f; acc[2 * t + 1] = 0.f; adl[t] = ad[b * 256 + t];
  __syncthreads();
  int cnt = min((int)gCur[b], BCAP);
  const unsigned* bp = bucket + (size_t)b * BCAP;
  const unsigned SM = (1u << SBITS) - 1;
  int i = t;
  for (; i + 768 < cnt; i += 1024) {
    unsigned u0 = bp[i], u1 = bp[i + 256], u2 = bp[i + 512], u3 = bp[i + 768];
    float2 az0 = asz[u0 & SM], az1 = asz[u1 & SM], az2 = asz[u2 & SM], az3 = asz[u3 & SM];
    int l0 = u0 >> SBITS, l1 = u1 >> SBITS, l2 = u2 >> SBITS, l3 = u3 >> SBITS;
    float ea0 = __expf(lrelu(az0.x + adl[l0]));
    float ea1 = __expf(lrelu(az1.x + adl[l1]));
    float ea2 = __expf(lrelu(az2.x + adl[l2]));
    float ea3 = __expf(lrelu(az3.x + adl[l3]));
    atomicAdd(&acc[2 * l0], ea0); atomicAdd(&acc[2 * l0 + 1], ea0 * az0.y);
    atomicAdd(&acc[2 * l1], ea1); atomicAdd(&acc[2 * l1 + 1], ea1 * az1.y);
    atomicAdd(&acc[2 * l2], ea2); atomicAdd(&acc[2 * l2 + 1], ea2 * az2.y);
    atomicAdd(&acc[2 * l3], ea3); atomicAdd(&acc[2 * l3 + 1], ea3 * az3.y);
  }
  for (; i < cnt; i += 256) {
    unsigned u = bp[i];
    float2 az = asz[u & SM];
    int l = u >> SBITS;
    float ea = __expf(lrelu(az.x + adl[l]));
    atomicAdd(&acc[2 * l], ea);
    atomicAdd(&acc[2 * l + 1], ea * az.y);
  }
  __syncthreads();
  float gb = *gbS;
  float itmp = 1.f / tmp[0];
  {
    int e = b * 256 + t;
    float2 szv = asz[e];
    float eself = __expf(lrelu(szv.x + adl[t]));  // softmax shift-invariant
    float la = (acc[2 * t + 1] + eself * szv.y) / (acc[2 * t] + eself) + gb;
    float ns = noise[e];
    float g = (logf(ns) - log1pf(-ns) + la) * itmp;
    float gate = 1.f / (1.f + __expf(-g));
    int key = row[e] * NN + col[e];
    unsigned hi = ((unsigned)key * 2654435761u) >> 14 & HMASK;
    while (true) {
      int old = atomicCAS(&hKeys[hi], -1, key);
      if (old == -1 || old == key) break;
      hi = (hi + 1) & HMASK;
    }
    eslot[e] = (int)hi;  // forward slot for the layer-1 fold (skips its probe)
    atomic_pk_add_f16(&hPair[hi], packh2(1.0f, gate));
  }
}

// layers 2/3 gather: padded csrW (w_bf16|row), 4-wide ILP.
__device__ __forceinline__ float2 gatherNodeP(const unsigned short* __restrict__ xb, int n, int lane,
                                              const int* __restrict__ cnt,
                                              const unsigned* __restrict__ csrW) {
  float2 sf = fp8x2f(xb[n * 64 + lane]);
  float a0 = sf.x, a1 = sf.y, ws = 0.f;
  int deg = min(cnt[n], DCAP);
  const unsigned* seg = csrW + n * DCAP;
  int i = 0;
  for (; i + 4 <= deg; i += 4) {
    unsigned q0 = seg[i], q1 = seg[i + 1], q2 = seg[i + 2], q3 = seg[i + 3];
    unsigned short u0 = xb[(q0 & 0x1fff) * 64 + lane];
    unsigned short u1 = xb[(q1 & 0x1fff) * 64 + lane];
    unsigned short u2 = xb[(q2 & 0x1fff) * 64 + lane];
    unsigned short u3 = xb[(q3 & 0x1fff) * 64 + lane];
    float w0 = bf1f(q0 >> 16), w1 = bf1f(q1 >> 16);
    float w2 = bf1f(q2 >> 16), w3 = bf1f(q3 >> 16);
    ws += w0 + w1 + w2 + w3;
    float2 f0 = fp8x2f(u0), f1 = fp8x2f(u1), f2v = fp8x2f(u2), f3 = fp8x2f(u3);
    a0 += w0 * f0.x + w1 * f1.x + w2 * f2v.x + w3 * f3.x;
    a1 += w0 * f0.y + w1 * f1.y + w2 * f2v.y + w3 * f3.y;
  }
  for (; i < deg; i++) {
    unsigned q = seg[i];
    unsigned short u = xb[(q & 0x1fff) * 64 + lane];
    float w = bf1f(q >> 16);
    ws += w;
    float2 f = fp8x2f(u);
    a0 += w * f.x;
    a1 += w * f.y;
  }
  float inv = 1.f / (1.f + ws);
  return make_float2(a0 * inv, a1 * inv);
}

// ---- GEMM: T in registers (lane L holds dims 2L,2L+1), W bf16 in 32KB LDS,
//      T[k] broadcast via scalar readlane ----
#define GEMM2(tv, acc)                                                   \
  {                                                                      \
    _Pragma("unroll") for (int j = 0; j < 2; j++) acc[j] = make_float2(0.f, 0.f); \
    _Pragma("unroll 16") for (int k2 = 0; k2 < 64; k2++) {               \
      float2 w0 = bf2f(Wl[(2 * k2) * 64 + lane]);                        \
      float2 w1 = bf2f(Wl[(2 * k2 + 1) * 64 + lane]);                    \
      _Pragma("unroll") for (int j = 0; j < 2; j++) {                    \
        float bx = rdlane(tv[j].x, k2);                                  \
        float by = rdlane(tv[j].y, k2);                                  \
        acc[j].x += bx * w0.x + by * w1.x;                               \
        acc[j].y += bx * w0.y + by * w1.y;                               \
      }                                                                  \
    }                                                                    \
  }

// F1: GCN layer 1, kE absorbed as a LANE-PARALLEL fold phase.
// Phase 1: 256 threads independently fold the block's <=320 (node,slot) edges
//          (hash probe each, like kE's one-thread-one-edge TLP), results to
//          LDS + csrW. Phase 2: gather with weights from LDS, GEMM, fp8 out.
__global__ __launch_bounds__(256) void kF1(const unsigned short* __restrict__ xb,
                                           const int* __restrict__ colCnt,
                                           const int* __restrict__ csrE,
                                           const int* __restrict__ row,
                                           const int* __restrict__ eslot,
                                           const unsigned* __restrict__ hPair,
                                           const int* __restrict__ hKeys,
                                           unsigned* __restrict__ csrW,
                                           const float* __restrict__ W,
                                           unsigned short* __restrict__ outB) {
  __shared__ unsigned Wl[128 * 64];   // bf16x2 weights
  __shared__ unsigned wl[8 * DCAP];   // per-slot (w_bf16|row)
  __shared__ int degl[8];
  int t = threadIdx.x, lane = t & 63, wv = t >> 6;
  int nb = blockIdx.x * 8;
  if (t < 8) degl[t] = min(colCnt[nb + t], DCAP);
  const float4* W4 = (const float4*)W;
  for (int i = t; i < 4096; i += 256) {
    float4 a = W4[i];
    ((uint2*)Wl)[i] = make_uint2(f2bf(a.x, a.y), f2bf(a.z, a.w));
  }
  __syncthreads();  // degl ready
  // ---- fold phase: slot = nl*DCAP + j, each thread independent ----
  for (int slot = t; slot < 8 * DCAP; slot += 256) {
    int nl = slot / DCAP, j = slot - nl * DCAP;
    if (j < degl[nl]) {
      int n = nb + nl;
      int e = csrE[n * DCAP + j];
      int r = row[e];
      unsigned u1 = hPair[eslot[e]];
      __half2 h1 = *reinterpret_cast<__half2*>(&u1);
      float cv = __low2float(h1), g1 = __high2float(h1);
      int s2 = hfind(hKeys, n * NN + r);  // reverse edge key: col*NN+row, col==n
      float g2 = 0.f;
      if (s2 >= 0) {
        unsigned u2 = hPair[s2];
        g2 = __high2float(*reinterpret_cast<__half2*>(&u2));
      }
      float em = cv * 0.5f * (g1 + g2);
      float w = 1.f / (1.f + __expf(-em));
      unsigned pk = (f2bf1(w) << 16) | (unsigned)r;
      wl[slot] = pk;
      csrW[n * DCAP + j] = pk;  // persist for layers 2/3
    }
  }
  __syncthreads();  // wl ready
  // ---- gather phase: 2 nodes/wave, weights from LDS ----
  float2 tv[2];
#pragma unroll
  for (int j = 0; j < 2; j++) {
    int nl = wv * 2 + j;
    int n = nb + nl;
    float2 sf = fp8x2f(xb[n * 64 + lane]);
    float a0 = sf.x, a1 = sf.y, ws = 0.f;
    int deg = degl[nl];
    const unsigned* seg = wl + nl * DCAP;
    int i = 0;
    for (; i + 4 <= deg; i += 4) {
      unsigned q0 = seg[i], q1 = seg[i + 1], q2 = seg[i + 2], q3 = seg[i + 3];
      unsigned short u0 = xb[(q0 & 0x1fff) * 64 + lane];
      unsigned short u1 = xb[(q1 & 0x1fff) * 64 + lane];
      unsigned short u2 = xb[(q2 & 0x1fff) * 64 + lane];
      unsigned short u3 = xb[(q3 & 0x1fff) * 64 + lane];
      float w0 = bf1f(q0 >> 16), w1 = bf1f(q1 >> 16);
      float w2 = bf1f(q2 >> 16), w3 = bf1f(q3 >> 16);
      ws += w0 + w1 + w2 + w3;
      float2 f0 = fp8x2f(u0), f1 = fp8x2f(u1), f2v = fp8x2f(u2), f3 = fp8x2f(u3);
      a0 += w0 * f0.x + w1 * f1.x + w2 * f2v.x + w3 * f3.x;
      a1 += w0 * f0.y + w1 * f1.y + w2 * f2v.y + w3 * f3.y;
    }
    for (; i < deg; i++) {
      unsigned q = seg[i];
      unsigned short u = xb[(q & 0x1fff) * 64 + lane];
      float w = bf1f(q >> 16);
      ws += w;
      float2 f = fp8x2f(u);
      a0 += w * f.x;
      a1 += w * f.y;
    }
    float inv = 1.f / (1.f + ws);
    tv[j] = make_float2(a0 * inv, a1 * inv);
  }
  float2 acc[2];
  GEMM2(tv, acc)
#pragma unroll
  for (int j = 0; j < 2; j++) {
    int n = nb + wv * 2 + j;
    outB[n * 64 + lane] = f2fp8x2(fmaxf(acc[j].x, 0.f), fmaxf(acc[j].y, 0.f));
  }
}

// F: GCN layer 2, padded-CSR gather. 8 nodes/block.
__global__ __launch_bounds__(256) void kF(const unsigned short* __restrict__ xb,
                                          const int* __restrict__ colCnt,
                                          const unsigned* __restrict__ csrW,
                                          const float* __restrict__ W,
                                          unsigned short* __restrict__ outB) {
  __shared__ unsigned Wl[128 * 64];
  int t = threadIdx.x, lane = t & 63, wv = t >> 6;
  const float4* W4 = (const float4*)W;
  for (int i = t; i < 4096; i += 256) {
    float4 a = W4[i];
    ((uint2*)Wl)[i] = make_uint2(f2bf(a.x, a.y), f2bf(a.z, a.w));
  }
  int nb = blockIdx.x * 8;
  float2 tv[2];
#pragma unroll
  for (int j = 0; j < 2; j++)
    tv[j] = gatherNodeP(xb, nb + wv * 2 + j, lane, colCnt, csrW);
  __syncthreads();
  float2 acc[2];
  GEMM2(tv, acc)
#pragma unroll
  for (int j = 0; j < 2; j++) {
    int n = nb + wv * 2 + j;
    outB[n * 64 + lane] = f2fp8x2(fmaxf(acc[j].x, 0.f), fmaxf(acc[j].y, 0.f));
  }
}

// H: layer3 + pool + final. Pool accumulation spread over 16 gvec copies.
__global__ __launch_bounds__(256) void kH(const unsigned short* __restrict__ xb,
                                          const int* __restrict__ colCnt,
                                          const unsigned* __restrict__ csrW,
                                          const float* __restrict__ W,
                                          const float* __restrict__ Wc,
                                          float* __restrict__ gvec, unsigned* __restrict__ done,
                                          float* __restrict__ out) {
  __shared__ unsigned Wl[128 * 64];
  int t = threadIdx.x, lane = t & 63, wv = t >> 6;
  const float4* W4 = (const float4*)W;
  for (int i = t; i < 4096; i += 256) {
    float4 a = W4[i];
    ((uint2*)Wl)[i] = make_uint2(f2bf(a.x, a.y), f2bf(a.z, a.w));
  }
  int nb = blockIdx.x * 8;
  float2 tv[2];
#pragma unroll
  for (int j = 0; j < 2; j++)
    tv[j] = gatherNodeP(xb, nb + wv * 2 + j, lane, colCnt, csrW);
  __syncthreads();
  float2 acc[2];
  GEMM2(tv, acc)
  // pool: H3 never written to memory
  float s0 = fmaxf(acc[0].x, 0.f) + fmaxf(acc[1].x, 0.f);
  float s1 = fmaxf(acc[0].y, 0.f) + fmaxf(acc[1].y, 0.f);
  __syncthreads();  // GEMM done reading Wl; reuse as scratch
  float* gpart = (float*)Wl;
  unsigned* flagp = (unsigned*)Wl + 600;
  if (t < 128) gpart[t] = 0.f;
  __syncthreads();
  atomicAdd(&gpart[2 * lane], s0);
  atomicAdd(&gpart[2 * lane + 1], s1);
  __syncthreads();
  if (t < 128) atomicAdd(&gvec[((blockIdx.x & 15) << 7) + t], gpart[t]);
  asm volatile("s_waitcnt vmcnt(0)" ::: "memory");  // gvec atomics complete (memory-side)
  __syncthreads();
  if (t == 0) *flagp = (atomicAdd(done, 1u) == gridDim.x - 1) ? 1u : 0u;
  __syncthreads();
  if (*flagp) {
    float* f0 = (float*)Wl + 256;
    float* f1 = (float*)Wl + 384;
    if (t < 128) {
      float gj = 0.f;
#pragma unroll
      for (int k = 0; k < 16; k++) gj += atomicAdd(&gvec[k * 128 + t], 0.f);  // memory-side reads
      gj *= (1.0f / 8192.0f);
      f0[t] = gj * Wc[t * 2 + 0];
      f1[t] = gj * Wc[t * 2 + 1];
    }
    __syncthreads();
    for (int o = 64; o > 0; o >>= 1) {
      if (t < o) { f0[t] += f0[t + o]; f1[t] += f1[t + o]; }
      __syncthreads();
    }
    if (t == 0) {
      float l0 = f0[0], l1 = f1[0];
      float m = fmaxf(l0, l1);
      float e0 = __expf(l0 - m), e1 = __expf(l1 - m);
      float inv = 1.f / (e0 + e1);
      out[0] = e0 * inv;
      out[1] = e1 * inv;
    }
  }
}

extern "C" void kernel_launch(void* const* d_in, const int* in_sizes, int n_in,
                              void* d_out, int out_size, void* d_ws, size_t ws_size,
                              hipStream_t stream) {
  const float* x     = (const float*)d_in[0];
  const float* embed = (const float*)d_in[1];
  const float* noise = (const float*)d_in[2];
  const float* tmp   = (const float*)d_in[3];
  const float* gat_W = (const float*)d_in[4];
  const float* att_s = (const float*)d_in[5];
  const float* att_d = (const float*)d_in[6];
  const float* gat_b = (const float*)d_in[7];
  const float* lin_W = (const float*)d_in[8];
  const float* lin_b = (const float*)d_in[9];
  const float* W1    = (const float*)d_in[10];
  const float* W2    = (const float*)d_in[11];
  const float* W3    = (const float*)d_in[12];
  const float* Wc    = (const float*)d_in[13];
  const int* ei      = (const int*)d_in[14];
  const int* nei     = (const int*)d_in[15];
  const int* row = ei;
  const int* col = ei + EE;
  const int* src2 = nei;
  const int* dst2 = nei + E2C;
  float* out = (float*)d_out;

  // workspace layout (4-byte units); 16B/8B-aligned buffers first
  char* w8 = (char*)d_ws;
  size_t off = 0;
  auto alloc = [&](size_t units) -> void* {
    void* p = w8 + off * 4;
    off += units;
    return p;
  };
  float4*   pN      = (float4*)alloc(4 * NN);
  float4*   qN      = (float4*)alloc(4 * NN);
  float2*   asz     = (float2*)alloc(2 * EE);
  unsigned short* xbu = (unsigned short*)alloc(NN * 32);  // fp8x2 per lane
  unsigned short* H1u = (unsigned short*)alloc(NN * 32);
  unsigned short* H2u = (unsigned short*)alloc(NN * 32);
  unsigned* csrW    = (unsigned*)alloc(NN * DCAP);  // padded (w_bf16|row)
  int*      csrE    = (int*)alloc(NN * DCAP);       // padded edge ids
  float*    ad      = (float*)alloc(EE);
  int*      eslot   = (int*)alloc(EE);
  int*      colCnt  = (int*)alloc(NN);
  int*      hKeys   = (int*)alloc(HSZ);
  unsigned* hPair   = (unsigned*)alloc(HSZ);
  unsigned* bucket  = (unsigned*)alloc((size_t)NBIN * BCAP);
  unsigned* gCur    = (unsigned*)alloc(NBIN);
  float*    gvec    = (float*)alloc(2048);  // 16 copies x 128
  unsigned* done    = (unsigned*)alloc(2);
  float*    gbS     = (float*)alloc(2);

  kA<<<512, 256, 0, stream>>>(x, embed, gat_W, att_s, att_d, lin_W, gat_b, lin_b,
                              pN, qN, xbu, hKeys, hPair, colCnt, gvec, done, gCur, gbS);
  kC<<<NBIN, 256, 0, stream>>>(row, col, pN, qN, asz, ad, colCnt, csrE, src2, dst2, gCur, bucket);
  kD<<<NBIN, 256, 0, stream>>>(row, col, asz, ad, bucket, gCur, gbS, noise, tmp,
                               hKeys, hPair, eslot);
  kF1<<<NN / 8, 256, 0, stream>>>(xbu, colCnt, csrE, row, eslot, hPair, hKeys, csrW, W1, H1u);
  kF<<<NN / 8, 256, 0, stream>>>(H1u, colCnt, csrW, W2, H2u);
  kH<<<NN / 8, 256, 0, stream>>>(H2u, colCnt, csrW, W3, Wc, gvec, done, out);
}